// Round 14
// baseline (701.292 us; speedup 1.0000x reference)
//
#include <hip/hip_runtime.h>
#include <hip/hip_bf16.h>
#include <cmath>

// Problem constants (match reference)
#define NN   20000     // nodes
#define NE   400000    // edges
#define NHID 512
#define HEADS 8
#define HD   64
#define FH   2048
#define NS   2000
#define LN_EPS 1e-5f
#define NSTRIP 16      // FH/128

typedef unsigned short ushort_t;
typedef __bf16 b16x8 __attribute__((ext_vector_type(8)));
typedef float  f32x4 __attribute__((ext_vector_type(4)));

__device__ __forceinline__ ushort_t f2bf(float f) {
    unsigned u = __builtin_bit_cast(unsigned, f);
    unsigned r = (u + 0x7FFFu + ((u >> 16) & 1u)) >> 16;   // RNE
    return (ushort_t)r;
}
__device__ __forceinline__ float bf2f(ushort_t u) {
    return __builtin_bit_cast(float, (unsigned)u << 16);
}

__device__ __forceinline__ void async16(ushort_t* lds, const ushort_t* g) {
    __builtin_amdgcn_global_load_lds(
        (const __attribute__((address_space(1))) void*)g,
        (__attribute__((address_space(3))) void*)lds,
        16, 0, 0);
}

// ---------------------------------------------------------------------------
// 128x128 bf16 MFMA GEMM (round-12 verified form, BK=64, 2-phase, swizzled).
// Used for z-GEMM (SCORES) and FFN2.
// ---------------------------------------------------------------------------
template<int RELU, int ACCUM, int OUT_BF16, int SCORES>
__global__ __launch_bounds__(256)
void mfma_gemm_nt(const ushort_t* __restrict__ A, const ushort_t* __restrict__ B,
                  void* __restrict__ Cv, const float* __restrict__ bias,
                  const float* __restrict__ al, const float* __restrict__ ar,
                  float* __restrict__ SS, float* __restrict__ SD,
                  int M, int N, int K, int lda, int ldb, int ldc)
{
    __shared__ ushort_t As[2][128 * 64];   // 32 KB
    __shared__ ushort_t Bs[2][128 * 64];   // 32 KB
    const int tid  = threadIdx.x;
    const int lane = tid & 63;
    const int w    = tid >> 6;        // wave 0..3
    const int wm   = w >> 1, wn = w & 1;
    const int m0 = blockIdx.y * 128, n0 = blockIdx.x * 128;

    const int scol = ((lane & 7) ^ (lane >> 3)) * 8;
    const ushort_t* ap[4];
    const ushort_t* bp[4];
    int ldsoff[4];
#pragma unroll
    for (int i = 0; i < 4; ++i) {
        const int r = w * 32 + i * 8 + (lane >> 3);
        const int gm = min(m0 + r, M - 1);                // clamp tail tile
        ap[i] = A + (size_t)gm * lda + scol;
        bp[i] = B + (size_t)(n0 + r) * ldb + scol;        // n0+r < N always
        ldsoff[i] = (w * 32 + i * 8) * 64 + lane * 8;
    }

    f32x4 acc[4][4] = {};

    const int nt = K >> 6;   // K/64 tiles
#pragma unroll
    for (int i = 0; i < 4; ++i) {
        async16(&As[0][ldsoff[i]], ap[i]);
        async16(&Bs[0][ldsoff[i]], bp[i]);
    }
    __syncthreads();   // vmcnt(0) drain -> buf0 ready

    const int fr = lane & 15, fk8 = lane >> 4;   // fragment row, k-chunk 0..3
    const int key = fr & 7;                      // read-side swizzle key

    for (int t = 0; t < nt; ++t) {
        const int cur = t & 1;
        if (t + 1 < nt) {   // issue next-tile loads FIRST (overlap with compute)
            const int ko = (t + 1) << 6;
#pragma unroll
            for (int i = 0; i < 4; ++i) {
                async16(&As[cur ^ 1][ldsoff[i]], ap[i] + ko);
                async16(&Bs[cur ^ 1][ldsoff[i]], bp[i] + ko);
            }
        }
#pragma unroll
        for (int ks = 0; ks < 2; ++ks) {         // two 32-K subtiles
            const int pc = ((ks * 4 + fk8) ^ key) * 8;   // swizzled chunk offset
            b16x8 af[4], bg[4];
#pragma unroll
            for (int m = 0; m < 4; ++m)
                af[m] = *reinterpret_cast<const b16x8*>(
                    &As[cur][(wm * 64 + m * 16 + fr) * 64 + pc]);
#pragma unroll
            for (int n = 0; n < 4; ++n)
                bg[n] = *reinterpret_cast<const b16x8*>(
                    &Bs[cur][(wn * 64 + n * 16 + fr) * 64 + pc]);
#pragma unroll
            for (int m = 0; m < 4; ++m)
#pragma unroll
                for (int n = 0; n < 4; ++n)
                    acc[m][n] = __builtin_amdgcn_mfma_f32_16x16x32_bf16(
                        bg[n], af[m], acc[m][n], 0, 0, 0);   // swapped -> C^T
        }
        __syncthreads();   // drains vmcnt (prefetch landed) + seals buf reads
    }

    // epilogue (transposed frag): row = ...+ma*16+fr ; cols = ...+nb*16+fq*4+{0..3}
    const int fq = lane >> 4;
    const int h = (n0 >> 6) + wn;           // head (SCORES mode; 64-col blocks)
    ushort_t* Cb = (ushort_t*)Cv;
    float*    Cf = (float*)Cv;

#pragma unroll
    for (int ma = 0; ma < 4; ++ma) {
        const int row = m0 + wm * 64 + ma * 16 + fr;
        const bool rowok = row < M;
        float pa = 0.f, pb = 0.f;
#pragma unroll
        for (int nb = 0; nb < 4; ++nb) {
            const int col0 = n0 + wn * 64 + nb * 16 + fq * 4;
            float v[4];
#pragma unroll
            for (int r = 0; r < 4; ++r) v[r] = acc[ma][nb][r];
            if (bias) {
                const float4 bb = *reinterpret_cast<const float4*>(&bias[col0]);
                v[0] += bb.x; v[1] += bb.y; v[2] += bb.z; v[3] += bb.w;
            }
            if (RELU) {
#pragma unroll
                for (int r = 0; r < 4; ++r) v[r] = fmaxf(v[r], 0.f);
            }
            if constexpr (SCORES) {
                const int d0 = nb * 16 + fq * 4;   // dim within head
#pragma unroll
                for (int r = 0; r < 4; ++r) {
                    pa = fmaf(v[r], al[h * HD + d0 + r], pa);
                    pb = fmaf(v[r], ar[h * HD + d0 + r], pb);
                }
            }
            if (rowok) {
                if constexpr (OUT_BF16) {
                    ushort4 u = make_ushort4(f2bf(v[0]), f2bf(v[1]), f2bf(v[2]), f2bf(v[3]));
                    *reinterpret_cast<ushort4*>(&Cb[(size_t)row * ldc + col0]) = u;
                } else {
                    float4* cp = reinterpret_cast<float4*>(&Cf[(size_t)row * ldc + col0]);
                    if (ACCUM) {
                        float4 o = *cp;
                        o.x += v[0]; o.y += v[1]; o.z += v[2]; o.w += v[3];
                        *cp = o;
                    } else {
                        *cp = make_float4(v[0], v[1], v[2], v[3]);
                    }
                }
            }
        }
        if constexpr (SCORES) {
            pa += __shfl_xor(pa, 16); pa += __shfl_xor(pa, 32);
            pb += __shfl_xor(pb, 16); pb += __shfl_xor(pb, 32);
            if (fq == 0 && rowok) {
                SS[row * HEADS + h] = pa;
                SD[row * HEADS + h] = pb;
            }
        }
    }
}

// ---------------------------------------------------------------------------
// ROUND-14: persistent A-resident FFN1 kernel.
// Evidence: FFN-GEMM time invariant to barriers/prefetch/bytes; FETCH=84MB is
// 4x compulsory reads -> the A panel (20.5MB > per-XCD L2) is re-swept from
// L3/HBM once per n-strip (16x). Fix: A m-tile resident in LDS (128KB,
// ktile-major: 8 x [128x64] tiles, each laid out EXACTLY like the verified
// kernel's As); loop n-strips inside a persistent block -> A read ~once.
// B strip staged per K-step (16KB, single-buffered, L2-hot), round-12
// staging/swizzle/fragment/epilogue formulas verbatim. 2512 items m-major,
// grid 256, ~10 items/block -> A restaged <=2x/block. Requires CH == FH.
// ---------------------------------------------------------------------------
__global__ __launch_bounds__(256)
void ffn1_persistent(const ushort_t* __restrict__ A,   // Hb [M][NHID]
                     const ushort_t* __restrict__ B,   // w1b [FH][NHID]
                     ushort_t* __restrict__ C,         // MIDb [M][FH]
                     const float* __restrict__ bias,   // b1 [FH]
                     int M)
{
    __shared__ ushort_t A8[8][128 * 64];   // 128 KB resident A m-tile
    __shared__ ushort_t Bsb[128 * 64];     // 16 KB current B strip ktile
    const int tid  = threadIdx.x;
    const int lane = tid & 63;
    const int w    = tid >> 6;
    const int wm   = w >> 1, wn = w & 1;

    const int MT  = (M + 127) >> 7;
    const int IT  = MT * NSTRIP;
    const int per = (IT + (int)gridDim.x - 1) / (int)gridDim.x;
    const int it0 = blockIdx.x * per;
    const int it1 = min(it0 + per, IT);

    const int scol = ((lane & 7) ^ (lane >> 3)) * 8;   // swizzled global k-off
    const int rr   = lane >> 3;                        // row 0..7 in 8-row group
    const int fr = lane & 15, fk8 = lane >> 4;
    const int key = fr & 7;
    const int fq = lane >> 4;

    int cur_m = -1;

    for (int it = it0; it < it1; ++it) {
        const int m  = it >> 4;            // m-major: consecutive its share m
        const int s  = it & 15;
        const int m0 = m << 7;
        const int n0 = s << 7;

        if (m != cur_m) {
            __syncthreads();               // seal prior A8/Bsb reads
#pragma unroll
            for (int kt = 0; kt < 8; ++kt) {
#pragma unroll
                for (int i = 0; i < 4; ++i) {
                    const int r = w * 32 + i * 8 + rr;
                    const int gm = min(m0 + r, M - 1);
                    async16(&A8[kt][(w * 32 + i * 8) * 64 + lane * 8],
                            A + (size_t)gm * NHID + kt * 64 + scol);
                }
            }
            cur_m = m;                     // drained by next K-step's 2nd barrier
        }

        f32x4 acc[4][4] = {};
        for (int t = 0; t < 8; ++t) {      // 8 K-tiles of 64 (K = NHID = 512)
            __syncthreads();               // seal prior Bsb reads
#pragma unroll
            for (int i = 0; i < 4; ++i) {
                const int r = w * 32 + i * 8 + rr;
                async16(&Bsb[(w * 32 + i * 8) * 64 + lane * 8],
                        B + (size_t)(n0 + r) * NHID + t * 64 + scol);
            }
            __syncthreads();               // vmcnt(0) drain -> Bsb (+A8) ready
#pragma unroll
            for (int ks = 0; ks < 2; ++ks) {
                const int pc = ((ks * 4 + fk8) ^ key) * 8;
                b16x8 af[4], bg[4];
#pragma unroll
                for (int mm = 0; mm < 4; ++mm)
                    af[mm] = *reinterpret_cast<const b16x8*>(
                        &A8[t][(wm * 64 + mm * 16 + fr) * 64 + pc]);
#pragma unroll
                for (int nn = 0; nn < 4; ++nn)
                    bg[nn] = *reinterpret_cast<const b16x8*>(
                        &Bsb[(wn * 64 + nn * 16 + fr) * 64 + pc]);
#pragma unroll
                for (int mm = 0; mm < 4; ++mm)
#pragma unroll
                    for (int nn = 0; nn < 4; ++nn)
                        acc[mm][nn] = __builtin_amdgcn_mfma_f32_16x16x32_bf16(
                            bg[nn], af[mm], acc[mm][nn], 0, 0, 0);  // C^T frag
            }
        }

        // epilogue (round-12 verbatim): RELU + bias, bf16 out, ldc = FH
#pragma unroll
        for (int ma = 0; ma < 4; ++ma) {
            const int row = m0 + wm * 64 + ma * 16 + fr;
            if (row >= M) continue;
#pragma unroll
            for (int nb = 0; nb < 4; ++nb) {
                const int col0 = n0 + wn * 64 + nb * 16 + fq * 4;
                float v[4];
#pragma unroll
                for (int r = 0; r < 4; ++r) v[r] = acc[ma][nb][r];
                const float4 bb = *reinterpret_cast<const float4*>(&bias[col0]);
                v[0] += bb.x; v[1] += bb.y; v[2] += bb.z; v[3] += bb.w;
#pragma unroll
                for (int r = 0; r < 4; ++r) v[r] = fmaxf(v[r], 0.f);
                ushort4 u = make_ushort4(f2bf(v[0]), f2bf(v[1]), f2bf(v[2]), f2bf(v[3]));
                *reinterpret_cast<ushort4*>(&C[(size_t)row * FH + col0]) = u;
            }
        }
    }
}

// ---------------------------------------------------------------------------
// fp32 -> bf16 conversion, 4 elems/thread (n % 4 == 0)
// ---------------------------------------------------------------------------
__global__ void f2b_kernel(const float* __restrict__ x, ushort_t* __restrict__ y, int n)
{
    int i = (blockIdx.x * 256 + threadIdx.x) * 4;
    if (i >= n) return;
    const float4 v = *reinterpret_cast<const float4*>(&x[i]);
    ushort2 a = make_ushort2(f2bf(v.x), f2bf(v.y));
    ushort2 b = make_ushort2(f2bf(v.z), f2bf(v.w));
    *reinterpret_cast<ushort2*>(&y[i])     = a;
    *reinterpret_cast<ushort2*>(&y[i + 2]) = b;
}

// feats -> H (fp32 copy) + Hb (bf16), one pass
__global__ void feats_init(const float* __restrict__ x, float* __restrict__ H,
                           ushort_t* __restrict__ Hb, int n)
{
    int i = (blockIdx.x * 256 + threadIdx.x) * 4;
    if (i >= n) return;
    const float4 v = *reinterpret_cast<const float4*>(&x[i]);
    *reinterpret_cast<float4*>(&H[i]) = v;
    *reinterpret_cast<ushort4*>(&Hb[i]) =
        make_ushort4(f2bf(v.x), f2bf(v.y), f2bf(v.z), f2bf(v.w));
}

// Repack Wh[h][f][d] (one prop step) -> Wp[col][f] bf16, col = h*64+d
__global__ void repack_wb(const float* __restrict__ Wh, ushort_t* __restrict__ Wp)
{
    int idx = blockIdx.x * 256 + threadIdx.x;
    if (idx >= NHID * NHID) return;
    int col = idx >> 9, f = idx & 511;
    int h = col >> 6, d = col & 63;
    Wp[idx] = f2bf(Wh[((size_t)h * NHID + f) * HD + d]);
}

// ---------------------------------------------------------------------------
// CSR build
// ---------------------------------------------------------------------------
__global__ void count_deg(const int* __restrict__ dst, int* __restrict__ deg)
{
    int e = blockIdx.x * 256 + threadIdx.x;
    if (e < NE) atomicAdd(&deg[dst[e]], 1);
}

__global__ __launch_bounds__(1024)
void scan_deg(const int* __restrict__ deg, int* __restrict__ rowptr)
{
    __shared__ int part[1024];
    const int tid = threadIdx.x;
    const int per = (NN + 1023) / 1024;
    const int start = tid * per;
    int s = 0;
    for (int j = 0; j < per; ++j)
        if (start + j < NN) s += deg[start + j];
    part[tid] = s;
    __syncthreads();
    for (int off = 1; off < 1024; off <<= 1) {
        int v = (tid >= off) ? part[tid - off] : 0;
        __syncthreads();
        part[tid] += v;
        __syncthreads();
    }
    int prefix = (tid == 0) ? 0 : part[tid - 1];
    for (int j = 0; j < per; ++j) {
        if (start + j < NN) {
            rowptr[start + j] = prefix;
            prefix += deg[start + j];
        }
    }
    if (tid == 1023) rowptr[NN] = part[1023];
}

__global__ void copy_int(const int* __restrict__ a, int* __restrict__ b, int n)
{
    int i = blockIdx.x * 256 + threadIdx.x;
    if (i < n) b[i] = a[i];
}

__global__ void scatter_edges(const int* __restrict__ src, const int* __restrict__ dst,
                              int* __restrict__ cursor, int* __restrict__ csrc)
{
    int e = blockIdx.x * 256 + threadIdx.x;
    if (e < NE) {
        int p = atomicAdd(&cursor[dst[e]], 1);
        csrc[p] = src[e];
    }
}

// ---------------------------------------------------------------------------
// Per-dst-node online segment-softmax + aggregation, fused ELU + residual.
// Phase C unrolled x8 (8 independent z gathers in flight). Round-11 form.
// ---------------------------------------------------------------------------
__global__ __launch_bounds__(256)
void gat_aggregate(const ushort_t* __restrict__ Zb, const float* __restrict__ SS,
                   const float* __restrict__ SD, const int* __restrict__ rowptr,
                   const int* __restrict__ csrc, float* __restrict__ H,
                   ushort_t* __restrict__ Hb)
{
    const int n = blockIdx.x;
    const int tid = threadIdx.x;
    __shared__ float sdst_sh[8];
    __shared__ float v_sh[128 * 9];   // [j][h], stride 9 -> conflict-free
    __shared__ int   src_sh[128];

    const int rp0 = rowptr[n];
    const int deg = rowptr[n + 1] - rp0;

    if (tid < 8) sdst_sh[tid] = SD[n * HEADS + tid];
    __syncthreads();

    const int g32 = tid & 31;      // lane within head group
    const int h   = tid >> 5;      // head 0..7 (== (tid*2)>>6)
    const int d0  = tid * 2;       // this thread's two output dims
    float m_run = -1e30f, s_run = 0.f;
    float accx = 0.f, accy = 0.f;

    for (int base = 0; base < deg; base += 128) {
        const int cnt = min(128, deg - base);
        // A: gather scores ONCE into LDS (leaky-relu applied)
        for (int idx = tid; idx < cnt * 8; idx += 256) {
            const int j = idx >> 3, hh = idx & 7;
            const int s = csrc[rp0 + base + j];
            if (hh == 0) src_sh[j] = s;
            const float x = SS[s * HEADS + hh] + sdst_sh[hh];
            v_sh[j * 9 + hh] = x > 0.f ? x : 0.01f * x;
        }
        __syncthreads();
        // B: per-head chunk max -> exp -> sum
        float cm = -1e30f;
#pragma unroll
        for (int k = 0; k < 4; ++k) {
            const int j = g32 + k * 32;
            if (j < cnt) cm = fmaxf(cm, v_sh[j * 9 + h]);
        }
#pragma unroll
        for (int off = 1; off < 32; off <<= 1) cm = fmaxf(cm, __shfl_xor(cm, off));
        const float m_new = fmaxf(m_run, cm);
        const float f = expf(m_run - m_new);
        float ps = 0.f;
#pragma unroll
        for (int k = 0; k < 4; ++k) {
            const int j = g32 + k * 32;
            if (j < cnt) {
                const float e = expf(v_sh[j * 9 + h] - m_new);
                v_sh[j * 9 + h] = e;
                ps += e;
            }
        }
#pragma unroll
        for (int off = 1; off < 32; off <<= 1) ps += __shfl_xor(ps, off);
        s_run = s_run * f + ps;
        m_run = m_new;
        accx *= f; accy *= f;
        __syncthreads();
        // C: accumulate unnormalized alpha * z — unroll 8 for MLP
        int j = 0;
        for (; j + 8 <= cnt; j += 8) {
            int   sv[8];
            float av[8];
            ushort2 zv[8];
#pragma unroll
            for (int u = 0; u < 8; ++u) {
                sv[u] = src_sh[j + u];
                av[u] = v_sh[(j + u) * 9 + h];
            }
#pragma unroll
            for (int u = 0; u < 8; ++u)
                zv[u] = *reinterpret_cast<const ushort2*>(&Zb[(size_t)sv[u] * NHID + d0]);
#pragma unroll
            for (int u = 0; u < 8; ++u) {
                accx = fmaf(av[u], bf2f(zv[u].x), accx);
                accy = fmaf(av[u], bf2f(zv[u].y), accy);
            }
        }
        for (; j < cnt; ++j) {
            const int s = src_sh[j];
            const float a = v_sh[j * 9 + h];
            const ushort2 zv = *reinterpret_cast<const ushort2*>(&Zb[(size_t)s * NHID + d0]);
            accx = fmaf(a, bf2f(zv.x), accx);
            accy = fmaf(a, bf2f(zv.y), accy);
        }
        __syncthreads();
    }

    const float inv = deg > 0 ? 1.f / s_run : 0.f;
    accx *= inv; accy *= inv;

    const size_t o = (size_t)n * NHID + d0;
    const float2 hv = *reinterpret_cast<const float2*>(&H[o]);
    const float ex = accx > 0.f ? accx : expm1f(accx);
    const float ey = accy > 0.f ? accy : expm1f(accy);
    const float rx = ex + hv.x, ry = ey + hv.y;
    *reinterpret_cast<float2*>(&H[o]) = make_float2(rx, ry);
    *reinterpret_cast<ushort2*>(&Hb[o]) = make_ushort2(f2bf(rx), f2bf(ry));
}

// ---------------------------------------------------------------------------
// LN( Y + b2 + H ) * g + b  -> H (fp32) and Hb (bf16)
// one wave per row; lane owns 8 CONSECUTIVE elems (float4 x2 loads/stores)
// ---------------------------------------------------------------------------
__global__ __launch_bounds__(256)
void ffn_ln(const float* __restrict__ Y, const float* __restrict__ b2,
            const float* __restrict__ gw, const float* __restrict__ bw,
            float* __restrict__ H, ushort_t* __restrict__ Hb)
{
    const int wave = threadIdx.x >> 6, lane = threadIdx.x & 63;
    const int n = blockIdx.x * 4 + wave;
    if (n >= NN) return;
    const int f0 = lane * 8;
    const size_t o = (size_t)n * NHID + f0;

    const float4 ya = *reinterpret_cast<const float4*>(&Y[o]);
    const float4 yb = *reinterpret_cast<const float4*>(&Y[o + 4]);
    const float4 ha = *reinterpret_cast<const float4*>(&H[o]);
    const float4 hb = *reinterpret_cast<const float4*>(&H[o + 4]);
    const float4 ba = *reinterpret_cast<const float4*>(&b2[f0]);
    const float4 bb = *reinterpret_cast<const float4*>(&b2[f0 + 4]);

    float v[8] = { ya.x + ba.x + ha.x, ya.y + ba.y + ha.y,
                   ya.z + ba.z + ha.z, ya.w + ba.w + ha.w,
                   yb.x + bb.x + hb.x, yb.y + bb.y + hb.y,
                   yb.z + bb.z + hb.z, yb.w + bb.w + hb.w };
    float sum = 0.f;
#pragma unroll
    for (int k = 0; k < 8; ++k) sum += v[k];
#pragma unroll
    for (int off = 1; off < 64; off <<= 1) sum += __shfl_xor(sum, off);
    const float mu = sum * (1.f / NHID);
    float var = 0.f;
#pragma unroll
    for (int k = 0; k < 8; ++k) { const float d = v[k] - mu; var = fmaf(d, d, var); }
#pragma unroll
    for (int off = 1; off < 64; off <<= 1) var += __shfl_xor(var, off);
    var *= (1.f / NHID);
    const float inv = rsqrtf(var + LN_EPS);

    const float4 ga = *reinterpret_cast<const float4*>(&gw[f0]);
    const float4 gb = *reinterpret_cast<const float4*>(&gw[f0 + 4]);
    const float4 wa = *reinterpret_cast<const float4*>(&bw[f0]);
    const float4 wb = *reinterpret_cast<const float4*>(&bw[f0 + 4]);
    const float gg[8] = { ga.x, ga.y, ga.z, ga.w, gb.x, gb.y, gb.z, gb.w };
    const float ww[8] = { wa.x, wa.y, wa.z, wa.w, wb.x, wb.y, wb.z, wb.w };

    float r[8];
#pragma unroll
    for (int k = 0; k < 8; ++k) r[k] = (v[k] - mu) * inv * gg[k] + ww[k];

    *reinterpret_cast<float4*>(&H[o])     = make_float4(r[0], r[1], r[2], r[3]);
    *reinterpret_cast<float4*>(&H[o + 4]) = make_float4(r[4], r[5], r[6], r[7]);
    *reinterpret_cast<ushort4*>(&Hb[o])     = make_ushort4(f2bf(r[0]), f2bf(r[1]), f2bf(r[2]), f2bf(r[3]));
    *reinterpret_cast<ushort4*>(&Hb[o + 4]) = make_ushort4(f2bf(r[4]), f2bf(r[5]), f2bf(r[6]), f2bf(r[7]));
}

__global__ void gather_out(const float* __restrict__ H, const int* __restrict__ sent,
                           float* __restrict__ out)
{
    int idx = blockIdx.x * 256 + threadIdx.x;   // 4 floats per thread
    if (idx >= NS * (NHID / 4)) return;
    const int s = idx >> 7, f = (idx & 127) * 4;
    const float4 v = *reinterpret_cast<const float4*>(&H[(size_t)sent[s] * NHID + f]);
    *reinterpret_cast<float4*>(&out[(size_t)s * NHID + f]) = v;
}

// ---------------------------------------------------------------------------
extern "C" void kernel_launch(void* const* d_in, const int* in_sizes, int n_in,
                              void* d_out, int out_size, void* d_ws, size_t ws_size,
                              hipStream_t stream)
{
    const float* feats = (const float*)d_in[0];
    const float* Wh    = (const float*)d_in[1];
    const float* al    = (const float*)d_in[2];
    const float* ar    = (const float*)d_in[3];
    const float* w1    = (const float*)d_in[4];
    const float* b1    = (const float*)d_in[5];
    const float* w2    = (const float*)d_in[6];
    const float* b2    = (const float*)d_in[7];
    const float* ln_g  = (const float*)d_in[8];
    const float* ln_b  = (const float*)d_in[9];
    const int* esrc    = (const int*)d_in[10];
    const int* edst    = (const int*)d_in[11];
    const int* sent    = (const int*)d_in[12];
    float* out = (float*)d_out;

    char* ws = (char*)d_ws;
    size_t off = 0;
    auto alloc = [&](size_t bytes) -> void* {
        void* p = ws + off;
        off = (off + bytes + 255) & ~(size_t)255;
        return p;
    };
    float*    H   = (float*)alloc((size_t)NN * NHID * 4);
    float*    Y   = (float*)alloc((size_t)NN * NHID * 4);   // FFN output (fp32)
    ushort_t* Hb  = (ushort_t*)alloc((size_t)NN * NHID * 2);
    ushort_t* Zb  = (ushort_t*)alloc((size_t)NN * NHID * 2);
    float*    SS  = (float*)alloc((size_t)NN * HEADS * 4);
    float*    SD  = (float*)alloc((size_t)NN * HEADS * 4);
    ushort_t* Wpb = (ushort_t*)alloc((size_t)NHID * NHID * 2);
    ushort_t* w1b = (ushort_t*)alloc((size_t)FH * NHID * 2);
    ushort_t* w2b = (ushort_t*)alloc((size_t)NHID * FH * 2);
    int* rowptr = (int*)alloc((NN + 1) * 4);
    int* deg    = (int*)alloc(NN * 4);
    int* cursor = (int*)alloc(NN * 4);
    int* csrc   = (int*)alloc((size_t)NE * 4);
    // FFN mid chunk (bf16): as large as remaining workspace allows
    int CH = FH;
    while (CH > 128 && off + (size_t)NN * CH * 2 > ws_size) CH >>= 1;
    ushort_t* MIDb = (ushort_t*)alloc((size_t)NN * CH * 2);

    // ---- CSR build ----
    hipMemsetAsync(deg, 0, NN * 4, stream);
    count_deg<<<(NE + 255) / 256, 256, 0, stream>>>(edst, deg);
    scan_deg<<<1, 1024, 0, stream>>>(deg, rowptr);
    copy_int<<<(NN + 255) / 256, 256, 0, stream>>>(rowptr, cursor, NN);
    scatter_edges<<<(NE + 255) / 256, 256, 0, stream>>>(esrc, edst, cursor, csrc);

    // ---- weights -> bf16 (once) ----
    f2b_kernel<<<(FH * NHID / 4 + 255) / 256, 256, 0, stream>>>(w1, w1b, FH * NHID);
    f2b_kernel<<<(NHID * FH / 4 + 255) / 256, 256, 0, stream>>>(w2, w2b, NHID * FH);

    // ---- h = feats (fp32 master + bf16 copy, one pass) ----
    feats_init<<<(NN * NHID / 4 + 255) / 256, 256, 0, stream>>>(feats, H, Hb, NN * NHID);

    const int MT = (NN + 127) / 128;   // 157 m-tiles
    for (int p = 0; p < 2; ++p) {
        // z = h @ Wh[p]  (bf16 MFMA, bf16 out) + fused attention scores
        repack_wb<<<(NHID * NHID + 255) / 256, 256, 0, stream>>>(
            Wh + (size_t)p * HEADS * NHID * HD, Wpb);
        mfma_gemm_nt<0, 0, 1, 1><<<dim3(NHID / 128, MT), 256, 0, stream>>>(
            Hb, Wpb, Zb, nullptr,
            al + (size_t)p * HEADS * HD, ar + (size_t)p * HEADS * HD, SS, SD,
            NN, NHID, NHID, NHID, NHID, NHID);
        // online segment softmax + aggregate + ELU + residual; H,Hb updated
        gat_aggregate<<<NN, 256, 0, stream>>>(Zb, SS, SD, rowptr, csrc, H, Hb);

        // FFN: Y = relu(Hb @ w1b.T + b1) @ w2b.T
        if (CH == FH) {
            // FFN1: persistent A-resident kernel (A read ~once vs 16 sweeps)
            ffn1_persistent<<<256, 256, 0, stream>>>(Hb, w1b, MIDb, b1, NN);
            mfma_gemm_nt<0, 0, 0, 0><<<dim3(NHID / 128, MT), 256, 0, stream>>>(
                MIDb, w2b, Y, nullptr,
                nullptr, nullptr, nullptr, nullptr,
                NN, NHID, FH, FH, FH, NHID);
        } else {
            for (int c0 = 0; c0 < FH; c0 += CH) {
                mfma_gemm_nt<1, 0, 1, 0><<<dim3(CH / 128, MT), 256, 0, stream>>>(
                    Hb, w1b + (size_t)c0 * NHID, MIDb, b1 + c0,
                    nullptr, nullptr, nullptr, nullptr,
                    NN, CH, NHID, NHID, NHID, CH);
                if (c0 == 0)
                    mfma_gemm_nt<0, 0, 0, 0><<<dim3(NHID / 128, MT), 256, 0, stream>>>(
                        MIDb, w2b + c0, Y, nullptr,
                        nullptr, nullptr, nullptr, nullptr,
                        NN, NHID, CH, CH, FH, NHID);
                else
                    mfma_gemm_nt<0, 1, 0, 0><<<dim3(NHID / 128, MT), 256, 0, stream>>>(
                        MIDb, w2b + c0, Y, nullptr,
                        nullptr, nullptr, nullptr, nullptr,
                        NN, NHID, CH, CH, FH, NHID);
            }
        }
        // LN(Y + b2 + residual) -> H, Hb
        ffn_ln<<<(NN + 3) / 4, 256, 0, stream>>>(Y, b2, ln_g, ln_b, H, Hb);
    }

    gather_out<<<(NS * NHID / 4 + 255) / 256, 256, 0, stream>>>(H, sent, out);
}

// Round 15
// 675.057 us; speedup vs baseline: 1.0389x; 1.0389x over previous
//
#include <hip/hip_runtime.h>
#include <hip/hip_bf16.h>
#include <cmath>

// Problem constants (match reference)
#define NN   20000     // nodes
#define NE   400000    // edges
#define NHID 512
#define HEADS 8
#define HD   64
#define FH   2048
#define NS   2000
#define LN_EPS 1e-5f

typedef unsigned short ushort_t;
typedef __bf16 b16x8 __attribute__((ext_vector_type(8)));
typedef float  f32x4 __attribute__((ext_vector_type(4)));

__device__ __forceinline__ ushort_t f2bf(float f) {
    unsigned u = __builtin_bit_cast(unsigned, f);
    unsigned r = (u + 0x7FFFu + ((u >> 16) & 1u)) >> 16;   // RNE
    return (ushort_t)r;
}
__device__ __forceinline__ float bf2f(ushort_t u) {
    return __builtin_bit_cast(float, (unsigned)u << 16);
}

__device__ __forceinline__ void async16(ushort_t* lds, const ushort_t* g) {
    __builtin_amdgcn_global_load_lds(
        (const __attribute__((address_space(1))) void*)g,
        (__attribute__((address_space(3))) void*)lds,
        16, 0, 0);
}

// ---------------------------------------------------------------------------
// 128x128 bf16 MFMA GEMM (round-12 verified form, BK=64, 2-phase, swizzled).
// ROUND-15: optional split-K via blockIdx.z — z offsets A,B by z*K and
// selects Cv (z=0) / Cv1 (z=1). Separate output buffers -> no RMW race;
// caller sums the halves. gridDim.z==1 reproduces round-12 exactly.
// ---------------------------------------------------------------------------
template<int RELU, int ACCUM, int OUT_BF16, int SCORES>
__global__ __launch_bounds__(256)
void mfma_gemm_nt(const ushort_t* __restrict__ A, const ushort_t* __restrict__ B,
                  void* __restrict__ Cv, void* __restrict__ Cv1,
                  const float* __restrict__ bias,
                  const float* __restrict__ al, const float* __restrict__ ar,
                  float* __restrict__ SS, float* __restrict__ SD,
                  int M, int N, int K, int lda, int ldb, int ldc)
{
    __shared__ ushort_t As[2][128 * 64];   // 32 KB
    __shared__ ushort_t Bs[2][128 * 64];   // 32 KB
    const int tid  = threadIdx.x;
    const int lane = tid & 63;
    const int w    = tid >> 6;        // wave 0..3
    const int wm   = w >> 1, wn = w & 1;
    const int m0 = blockIdx.y * 128, n0 = blockIdx.x * 128;

    const int kz = blockIdx.z;        // split-K plane
    A += (size_t)kz * K;              // k-offset within row (lda unchanged)
    B += (size_t)kz * K;

    const int scol = ((lane & 7) ^ (lane >> 3)) * 8;
    const ushort_t* ap[4];
    const ushort_t* bp[4];
    int ldsoff[4];
#pragma unroll
    for (int i = 0; i < 4; ++i) {
        const int r = w * 32 + i * 8 + (lane >> 3);
        const int gm = min(m0 + r, M - 1);                // clamp tail tile
        ap[i] = A + (size_t)gm * lda + scol;
        bp[i] = B + (size_t)(n0 + r) * ldb + scol;        // n0+r < N always
        ldsoff[i] = (w * 32 + i * 8) * 64 + lane * 8;
    }

    f32x4 acc[4][4] = {};

    const int nt = K >> 6;   // K/64 tiles
#pragma unroll
    for (int i = 0; i < 4; ++i) {
        async16(&As[0][ldsoff[i]], ap[i]);
        async16(&Bs[0][ldsoff[i]], bp[i]);
    }
    __syncthreads();   // vmcnt(0) drain -> buf0 ready

    const int fr = lane & 15, fk8 = lane >> 4;   // fragment row, k-chunk 0..3
    const int key = fr & 7;                      // read-side swizzle key

    for (int t = 0; t < nt; ++t) {
        const int cur = t & 1;
        if (t + 1 < nt) {   // issue next-tile loads FIRST (overlap with compute)
            const int ko = (t + 1) << 6;
#pragma unroll
            for (int i = 0; i < 4; ++i) {
                async16(&As[cur ^ 1][ldsoff[i]], ap[i] + ko);
                async16(&Bs[cur ^ 1][ldsoff[i]], bp[i] + ko);
            }
        }
#pragma unroll
        for (int ks = 0; ks < 2; ++ks) {         // two 32-K subtiles
            const int pc = ((ks * 4 + fk8) ^ key) * 8;   // swizzled chunk offset
            b16x8 af[4], bg[4];
#pragma unroll
            for (int m = 0; m < 4; ++m)
                af[m] = *reinterpret_cast<const b16x8*>(
                    &As[cur][(wm * 64 + m * 16 + fr) * 64 + pc]);
#pragma unroll
            for (int n = 0; n < 4; ++n)
                bg[n] = *reinterpret_cast<const b16x8*>(
                    &Bs[cur][(wn * 64 + n * 16 + fr) * 64 + pc]);
#pragma unroll
            for (int m = 0; m < 4; ++m)
#pragma unroll
                for (int n = 0; n < 4; ++n)
                    acc[m][n] = __builtin_amdgcn_mfma_f32_16x16x32_bf16(
                        bg[n], af[m], acc[m][n], 0, 0, 0);   // swapped -> C^T
        }
        __syncthreads();   // drains vmcnt (prefetch landed) + seals buf reads
    }

    // epilogue (transposed frag): row = ...+ma*16+fr ; cols = ...+nb*16+fq*4+{0..3}
    const int fq = lane >> 4;
    const int h = (n0 >> 6) + wn;           // head (SCORES mode; 64-col blocks)
    ushort_t* Cb = (ushort_t*)Cv;
    float*    Cf = kz ? (float*)Cv1 : (float*)Cv;

#pragma unroll
    for (int ma = 0; ma < 4; ++ma) {
        const int row = m0 + wm * 64 + ma * 16 + fr;
        const bool rowok = row < M;
        float pa = 0.f, pb = 0.f;
#pragma unroll
        for (int nb = 0; nb < 4; ++nb) {
            const int col0 = n0 + wn * 64 + nb * 16 + fq * 4;
            float v[4];
#pragma unroll
            for (int r = 0; r < 4; ++r) v[r] = acc[ma][nb][r];
            if (bias) {
                const float4 bb = *reinterpret_cast<const float4*>(&bias[col0]);
                v[0] += bb.x; v[1] += bb.y; v[2] += bb.z; v[3] += bb.w;
            }
            if (RELU) {
#pragma unroll
                for (int r = 0; r < 4; ++r) v[r] = fmaxf(v[r], 0.f);
            }
            if constexpr (SCORES) {
                const int d0 = nb * 16 + fq * 4;   // dim within head
#pragma unroll
                for (int r = 0; r < 4; ++r) {
                    pa = fmaf(v[r], al[h * HD + d0 + r], pa);
                    pb = fmaf(v[r], ar[h * HD + d0 + r], pb);
                }
            }
            if (rowok) {
                if constexpr (OUT_BF16) {
                    ushort4 u = make_ushort4(f2bf(v[0]), f2bf(v[1]), f2bf(v[2]), f2bf(v[3]));
                    *reinterpret_cast<ushort4*>(&Cb[(size_t)row * ldc + col0]) = u;
                } else {
                    float4* cp = reinterpret_cast<float4*>(&Cf[(size_t)row * ldc + col0]);
                    if (ACCUM) {
                        float4 o = *cp;
                        o.x += v[0]; o.y += v[1]; o.z += v[2]; o.w += v[3];
                        *cp = o;
                    } else {
                        *cp = make_float4(v[0], v[1], v[2], v[3]);
                    }
                }
            }
        }
        if constexpr (SCORES) {
            pa += __shfl_xor(pa, 16); pa += __shfl_xor(pa, 32);
            pb += __shfl_xor(pb, 16); pb += __shfl_xor(pb, 32);
            if (fq == 0 && rowok) {
                SS[row * HEADS + h] = pa;
                SD[row * HEADS + h] = pb;
            }
        }
    }
}

// ---------------------------------------------------------------------------
// fp32 -> bf16 conversion, 4 elems/thread (n % 4 == 0)
// ---------------------------------------------------------------------------
__global__ void f2b_kernel(const float* __restrict__ x, ushort_t* __restrict__ y, int n)
{
    int i = (blockIdx.x * 256 + threadIdx.x) * 4;
    if (i >= n) return;
    const float4 v = *reinterpret_cast<const float4*>(&x[i]);
    ushort2 a = make_ushort2(f2bf(v.x), f2bf(v.y));
    ushort2 b = make_ushort2(f2bf(v.z), f2bf(v.w));
    *reinterpret_cast<ushort2*>(&y[i])     = a;
    *reinterpret_cast<ushort2*>(&y[i + 2]) = b;
}

// feats -> H (fp32 copy) + Hb (bf16), one pass
__global__ void feats_init(const float* __restrict__ x, float* __restrict__ H,
                           ushort_t* __restrict__ Hb, int n)
{
    int i = (blockIdx.x * 256 + threadIdx.x) * 4;
    if (i >= n) return;
    const float4 v = *reinterpret_cast<const float4*>(&x[i]);
    *reinterpret_cast<float4*>(&H[i]) = v;
    *reinterpret_cast<ushort4*>(&Hb[i]) =
        make_ushort4(f2bf(v.x), f2bf(v.y), f2bf(v.z), f2bf(v.w));
}

// Repack Wh[h][f][d] (one prop step) -> Wp[col][f] bf16, col = h*64+d
__global__ void repack_wb(const float* __restrict__ Wh, ushort_t* __restrict__ Wp)
{
    int idx = blockIdx.x * 256 + threadIdx.x;
    if (idx >= NHID * NHID) return;
    int col = idx >> 9, f = idx & 511;
    int h = col >> 6, d = col & 63;
    Wp[idx] = f2bf(Wh[((size_t)h * NHID + f) * HD + d]);
}

// ---------------------------------------------------------------------------
// CSR build
// ---------------------------------------------------------------------------
__global__ void count_deg(const int* __restrict__ dst, int* __restrict__ deg)
{
    int e = blockIdx.x * 256 + threadIdx.x;
    if (e < NE) atomicAdd(&deg[dst[e]], 1);
}

__global__ __launch_bounds__(1024)
void scan_deg(const int* __restrict__ deg, int* __restrict__ rowptr)
{
    __shared__ int part[1024];
    const int tid = threadIdx.x;
    const int per = (NN + 1023) / 1024;
    const int start = tid * per;
    int s = 0;
    for (int j = 0; j < per; ++j)
        if (start + j < NN) s += deg[start + j];
    part[tid] = s;
    __syncthreads();
    for (int off = 1; off < 1024; off <<= 1) {
        int v = (tid >= off) ? part[tid - off] : 0;
        __syncthreads();
        part[tid] += v;
        __syncthreads();
    }
    int prefix = (tid == 0) ? 0 : part[tid - 1];
    for (int j = 0; j < per; ++j) {
        if (start + j < NN) {
            rowptr[start + j] = prefix;
            prefix += deg[start + j];
        }
    }
    if (tid == 1023) rowptr[NN] = part[1023];
}

__global__ void copy_int(const int* __restrict__ a, int* __restrict__ b, int n)
{
    int i = blockIdx.x * 256 + threadIdx.x;
    if (i < n) b[i] = a[i];
}

__global__ void scatter_edges(const int* __restrict__ src, const int* __restrict__ dst,
                              int* __restrict__ cursor, int* __restrict__ csrc)
{
    int e = blockIdx.x * 256 + threadIdx.x;
    if (e < NE) {
        int p = atomicAdd(&cursor[dst[e]], 1);
        csrc[p] = src[e];
    }
}

// ---------------------------------------------------------------------------
// Per-dst-node online segment-softmax + aggregation, fused ELU + residual.
// Phase C unrolled x8 (8 independent z gathers in flight). Round-11 form.
// ---------------------------------------------------------------------------
__global__ __launch_bounds__(256)
void gat_aggregate(const ushort_t* __restrict__ Zb, const float* __restrict__ SS,
                   const float* __restrict__ SD, const int* __restrict__ rowptr,
                   const int* __restrict__ csrc, float* __restrict__ H,
                   ushort_t* __restrict__ Hb)
{
    const int n = blockIdx.x;
    const int tid = threadIdx.x;
    __shared__ float sdst_sh[8];
    __shared__ float v_sh[128 * 9];   // [j][h], stride 9 -> conflict-free
    __shared__ int   src_sh[128];

    const int rp0 = rowptr[n];
    const int deg = rowptr[n + 1] - rp0;

    if (tid < 8) sdst_sh[tid] = SD[n * HEADS + tid];
    __syncthreads();

    const int g32 = tid & 31;      // lane within head group
    const int h   = tid >> 5;      // head 0..7 (== (tid*2)>>6)
    const int d0  = tid * 2;       // this thread's two output dims
    float m_run = -1e30f, s_run = 0.f;
    float accx = 0.f, accy = 0.f;

    for (int base = 0; base < deg; base += 128) {
        const int cnt = min(128, deg - base);
        // A: gather scores ONCE into LDS (leaky-relu applied)
        for (int idx = tid; idx < cnt * 8; idx += 256) {
            const int j = idx >> 3, hh = idx & 7;
            const int s = csrc[rp0 + base + j];
            if (hh == 0) src_sh[j] = s;
            const float x = SS[s * HEADS + hh] + sdst_sh[hh];
            v_sh[j * 9 + hh] = x > 0.f ? x : 0.01f * x;
        }
        __syncthreads();
        // B: per-head chunk max -> exp -> sum
        float cm = -1e30f;
#pragma unroll
        for (int k = 0; k < 4; ++k) {
            const int j = g32 + k * 32;
            if (j < cnt) cm = fmaxf(cm, v_sh[j * 9 + h]);
        }
#pragma unroll
        for (int off = 1; off < 32; off <<= 1) cm = fmaxf(cm, __shfl_xor(cm, off));
        const float m_new = fmaxf(m_run, cm);
        const float f = expf(m_run - m_new);
        float ps = 0.f;
#pragma unroll
        for (int k = 0; k < 4; ++k) {
            const int j = g32 + k * 32;
            if (j < cnt) {
                const float e = expf(v_sh[j * 9 + h] - m_new);
                v_sh[j * 9 + h] = e;
                ps += e;
            }
        }
#pragma unroll
        for (int off = 1; off < 32; off <<= 1) ps += __shfl_xor(ps, off);
        s_run = s_run * f + ps;
        m_run = m_new;
        accx *= f; accy *= f;
        __syncthreads();
        // C: accumulate unnormalized alpha * z — unroll 8 for MLP
        int j = 0;
        for (; j + 8 <= cnt; j += 8) {
            int   sv[8];
            float av[8];
            ushort2 zv[8];
#pragma unroll
            for (int u = 0; u < 8; ++u) {
                sv[u] = src_sh[j + u];
                av[u] = v_sh[(j + u) * 9 + h];
            }
#pragma unroll
            for (int u = 0; u < 8; ++u)
                zv[u] = *reinterpret_cast<const ushort2*>(&Zb[(size_t)sv[u] * NHID + d0]);
#pragma unroll
            for (int u = 0; u < 8; ++u) {
                accx = fmaf(av[u], bf2f(zv[u].x), accx);
                accy = fmaf(av[u], bf2f(zv[u].y), accy);
            }
        }
        for (; j < cnt; ++j) {
            const int s = src_sh[j];
            const float a = v_sh[j * 9 + h];
            const ushort2 zv = *reinterpret_cast<const ushort2*>(&Zb[(size_t)s * NHID + d0]);
            accx = fmaf(a, bf2f(zv.x), accx);
            accy = fmaf(a, bf2f(zv.y), accy);
        }
        __syncthreads();
    }

    const float inv = deg > 0 ? 1.f / s_run : 0.f;
    accx *= inv; accy *= inv;

    const size_t o = (size_t)n * NHID + d0;
    const float2 hv = *reinterpret_cast<const float2*>(&H[o]);
    const float ex = accx > 0.f ? accx : expm1f(accx);
    const float ey = accy > 0.f ? accy : expm1f(accy);
    const float rx = ex + hv.x, ry = ey + hv.y;
    *reinterpret_cast<float2*>(&H[o]) = make_float2(rx, ry);
    *reinterpret_cast<ushort2*>(&Hb[o]) = make_ushort2(f2bf(rx), f2bf(ry));
}

// ---------------------------------------------------------------------------
// LN( Y0 + Y1 + b2 + H ) * g + b  -> H (fp32) and Hb (bf16)
// one wave per row; lane owns 8 CONSECUTIVE elems (float4 x2 loads/stores)
// ---------------------------------------------------------------------------
__global__ __launch_bounds__(256)
void ffn_ln(const float* __restrict__ Y0, const float* __restrict__ Y1,
            const float* __restrict__ b2,
            const float* __restrict__ gw, const float* __restrict__ bw,
            float* __restrict__ H, ushort_t* __restrict__ Hb)
{
    const int wave = threadIdx.x >> 6, lane = threadIdx.x & 63;
    const int n = blockIdx.x * 4 + wave;
    if (n >= NN) return;
    const int f0 = lane * 8;
    const size_t o = (size_t)n * NHID + f0;

    const float4 ya = *reinterpret_cast<const float4*>(&Y0[o]);
    const float4 yb = *reinterpret_cast<const float4*>(&Y0[o + 4]);
    const float4 za = *reinterpret_cast<const float4*>(&Y1[o]);
    const float4 zb = *reinterpret_cast<const float4*>(&Y1[o + 4]);
    const float4 ha = *reinterpret_cast<const float4*>(&H[o]);
    const float4 hb = *reinterpret_cast<const float4*>(&H[o + 4]);
    const float4 ba = *reinterpret_cast<const float4*>(&b2[f0]);
    const float4 bb = *reinterpret_cast<const float4*>(&b2[f0 + 4]);

    float v[8] = { ya.x + za.x + ba.x + ha.x, ya.y + za.y + ba.y + ha.y,
                   ya.z + za.z + ba.z + ha.z, ya.w + za.w + ba.w + ha.w,
                   yb.x + zb.x + bb.x + hb.x, yb.y + zb.y + bb.y + hb.y,
                   yb.z + zb.z + bb.z + hb.z, yb.w + zb.w + bb.w + hb.w };
    float sum = 0.f;
#pragma unroll
    for (int k = 0; k < 8; ++k) sum += v[k];
#pragma unroll
    for (int off = 1; off < 64; off <<= 1) sum += __shfl_xor(sum, off);
    const float mu = sum * (1.f / NHID);
    float var = 0.f;
#pragma unroll
    for (int k = 0; k < 8; ++k) { const float d = v[k] - mu; var = fmaf(d, d, var); }
#pragma unroll
    for (int off = 1; off < 64; off <<= 1) var += __shfl_xor(var, off);
    var *= (1.f / NHID);
    const float inv = rsqrtf(var + LN_EPS);

    const float4 ga = *reinterpret_cast<const float4*>(&gw[f0]);
    const float4 gb = *reinterpret_cast<const float4*>(&gw[f0 + 4]);
    const float4 wa = *reinterpret_cast<const float4*>(&bw[f0]);
    const float4 wb = *reinterpret_cast<const float4*>(&bw[f0 + 4]);
    const float gg[8] = { ga.x, ga.y, ga.z, ga.w, gb.x, gb.y, gb.z, gb.w };
    const float ww[8] = { wa.x, wa.y, wa.z, wa.w, wb.x, wb.y, wb.z, wb.w };

    float r[8];
#pragma unroll
    for (int k = 0; k < 8; ++k) r[k] = (v[k] - mu) * inv * gg[k] + ww[k];

    *reinterpret_cast<float4*>(&H[o])     = make_float4(r[0], r[1], r[2], r[3]);
    *reinterpret_cast<float4*>(&H[o + 4]) = make_float4(r[4], r[5], r[6], r[7]);
    *reinterpret_cast<ushort4*>(&Hb[o])     = make_ushort4(f2bf(r[0]), f2bf(r[1]), f2bf(r[2]), f2bf(r[3]));
    *reinterpret_cast<ushort4*>(&Hb[o + 4]) = make_ushort4(f2bf(r[4]), f2bf(r[5]), f2bf(r[6]), f2bf(r[7]));
}

__global__ void gather_out(const float* __restrict__ H, const int* __restrict__ sent,
                           float* __restrict__ out)
{
    int idx = blockIdx.x * 256 + threadIdx.x;   // 4 floats per thread
    if (idx >= NS * (NHID / 4)) return;
    const int s = idx >> 7, f = (idx & 127) * 4;
    const float4 v = *reinterpret_cast<const float4*>(&H[(size_t)sent[s] * NHID + f]);
    *reinterpret_cast<float4*>(&out[(size_t)s * NHID + f]) = v;
}

// ---------------------------------------------------------------------------
extern "C" void kernel_launch(void* const* d_in, const int* in_sizes, int n_in,
                              void* d_out, int out_size, void* d_ws, size_t ws_size,
                              hipStream_t stream)
{
    const float* feats = (const float*)d_in[0];
    const float* Wh    = (const float*)d_in[1];
    const float* al    = (const float*)d_in[2];
    const float* ar    = (const float*)d_in[3];
    const float* w1    = (const float*)d_in[4];
    const float* b1    = (const float*)d_in[5];
    const float* w2    = (const float*)d_in[6];
    const float* b2    = (const float*)d_in[7];
    const float* ln_g  = (const float*)d_in[8];
    const float* ln_b  = (const float*)d_in[9];
    const int* esrc    = (const int*)d_in[10];
    const int* edst    = (const int*)d_in[11];
    const int* sent    = (const int*)d_in[12];
    float* out = (float*)d_out;

    char* ws = (char*)d_ws;
    size_t off = 0;
    auto alloc = [&](size_t bytes) -> void* {
        void* p = ws + off;
        off = (off + bytes + 255) & ~(size_t)255;
        return p;
    };
    float*    H   = (float*)alloc((size_t)NN * NHID * 4);
    float*    Y0  = (float*)alloc((size_t)NN * NHID * 4);   // FFN2 K-half 0
    float*    Y1  = (float*)alloc((size_t)NN * NHID * 4);   // FFN2 K-half 1
    ushort_t* Hb  = (ushort_t*)alloc((size_t)NN * NHID * 2);
    ushort_t* Zb  = (ushort_t*)alloc((size_t)NN * NHID * 2);
    float*    SS  = (float*)alloc((size_t)NN * HEADS * 4);
    float*    SD  = (float*)alloc((size_t)NN * HEADS * 4);
    ushort_t* Wpb = (ushort_t*)alloc((size_t)NHID * NHID * 2);
    ushort_t* w1b = (ushort_t*)alloc((size_t)FH * NHID * 2);
    ushort_t* w2b = (ushort_t*)alloc((size_t)NHID * FH * 2);
    int* rowptr = (int*)alloc((NN + 1) * 4);
    int* deg    = (int*)alloc(NN * 4);
    int* cursor = (int*)alloc(NN * 4);
    int* csrc   = (int*)alloc((size_t)NE * 4);
    // FFN mid chunk (bf16): as large as remaining workspace allows
    int CH = FH;
    while (CH > 256 && off + (size_t)NN * CH * 2 > ws_size) CH >>= 1;
    ushort_t* MIDb = (ushort_t*)alloc((size_t)NN * CH * 2);

    // ---- CSR build ----
    hipMemsetAsync(deg, 0, NN * 4, stream);
    count_deg<<<(NE + 255) / 256, 256, 0, stream>>>(edst, deg);
    scan_deg<<<1, 1024, 0, stream>>>(deg, rowptr);
    copy_int<<<(NN + 255) / 256, 256, 0, stream>>>(rowptr, cursor, NN);
    scatter_edges<<<(NE + 255) / 256, 256, 0, stream>>>(esrc, edst, cursor, csrc);

    // ---- weights -> bf16 (once) ----
    f2b_kernel<<<(FH * NHID / 4 + 255) / 256, 256, 0, stream>>>(w1, w1b, FH * NHID);
    f2b_kernel<<<(NHID * FH / 4 + 255) / 256, 256, 0, stream>>>(w2, w2b, NHID * FH);

    // ---- h = feats (fp32 master + bf16 copy, one pass) ----
    feats_init<<<(NN * NHID / 4 + 255) / 256, 256, 0, stream>>>(feats, H, Hb, NN * NHID);

    const int MT = (NN + 127) / 128;   // 157 m-tiles
    for (int p = 0; p < 2; ++p) {
        // z = h @ Wh[p]  (bf16 MFMA, bf16 out) + fused attention scores
        repack_wb<<<(NHID * NHID + 255) / 256, 256, 0, stream>>>(
            Wh + (size_t)p * HEADS * NHID * HD, Wpb);
        mfma_gemm_nt<0, 0, 1, 1><<<dim3(NHID / 128, MT), 256, 0, stream>>>(
            Hb, Wpb, Zb, nullptr, nullptr,
            al + (size_t)p * HEADS * HD, ar + (size_t)p * HEADS * HD, SS, SD,
            NN, NHID, NHID, NHID, NHID, NHID);
        // online segment softmax + aggregate + ELU + residual; H,Hb updated
        gat_aggregate<<<NN, 256, 0, stream>>>(Zb, SS, SD, rowptr, csrc, H, Hb);

        // FFN: Y0+Y1 = relu(Hb @ w1b.T + b1) @ w2b.T, chunked over FH;
        // FFN2 split-K=2 across blockIdx.z (separate Y0/Y1 -> no RMW race).
        for (int c0 = 0; c0 < FH; c0 += CH) {
            mfma_gemm_nt<1, 0, 1, 0><<<dim3(CH / 128, MT), 256, 0, stream>>>(
                Hb, w1b + (size_t)c0 * NHID, MIDb, nullptr, b1 + c0,
                nullptr, nullptr, nullptr, nullptr,
                NN, CH, NHID, NHID, NHID, CH);
            if (c0 == 0)
                mfma_gemm_nt<0, 0, 0, 0><<<dim3(NHID / 128, MT, 2), 256, 0, stream>>>(
                    MIDb, w2b + c0, Y0, Y1, nullptr,
                    nullptr, nullptr, nullptr, nullptr,
                    NN, NHID, CH / 2, CH, FH, NHID);
            else
                mfma_gemm_nt<0, 1, 0, 0><<<dim3(NHID / 128, MT, 2), 256, 0, stream>>>(
                    MIDb, w2b + c0, Y0, Y1, nullptr,
                    nullptr, nullptr, nullptr, nullptr,
                    NN, NHID, CH / 2, CH, FH, NHID);
        }
        // LN(Y0 + Y1 + b2 + residual) -> H, Hb
        ffn_ln<<<(NN + 3) / 4, 256, 0, stream>>>(Y0, Y1, b2, ln_g, ln_b, H, Hb);
    }

    gather_out<<<(NS * NHID / 4 + 255) / 256, 256, 0, stream>>>(H, sent, out);
}

// Round 16
// 485.379 us; speedup vs baseline: 1.4448x; 1.3908x over previous
//
#include <hip/hip_runtime.h>
#include <hip/hip_bf16.h>
#include <cmath>

// Problem constants (match reference)
#define NN   20000     // nodes
#define NE   400000    // edges
#define NHID 512
#define HEADS 8
#define HD   64
#define FH   2048
#define NS   2000
#define LN_EPS 1e-5f

typedef unsigned short ushort_t;
typedef __bf16 b16x8 __attribute__((ext_vector_type(8)));
typedef float  f32x4 __attribute__((ext_vector_type(4)));

__device__ __forceinline__ ushort_t f2bf(float f) {
    unsigned u = __builtin_bit_cast(unsigned, f);
    unsigned r = (u + 0x7FFFu + ((u >> 16) & 1u)) >> 16;   // RNE
    return (ushort_t)r;
}
__device__ __forceinline__ float bf2f(ushort_t u) {
    return __builtin_bit_cast(float, (unsigned)u << 16);
}

__device__ __forceinline__ void async16(ushort_t* lds, const ushort_t* g) {
    __builtin_amdgcn_global_load_lds(
        (const __attribute__((address_space(1))) void*)g,
        (__attribute__((address_space(3))) void*)lds,
        16, 0, 0);
}

// ---------------------------------------------------------------------------
// 128x128 bf16 MFMA GEMM (round-12 champion form, BK=64, 2-phase, swizzled).
// ---------------------------------------------------------------------------
template<int RELU, int ACCUM, int OUT_BF16, int SCORES>
__global__ __launch_bounds__(256)
void mfma_gemm_nt(const ushort_t* __restrict__ A, const ushort_t* __restrict__ B,
                  void* __restrict__ Cv, const float* __restrict__ bias,
                  const float* __restrict__ al, const float* __restrict__ ar,
                  float* __restrict__ SS, float* __restrict__ SD,
                  int M, int N, int K, int lda, int ldb, int ldc)
{
    __shared__ ushort_t As[2][128 * 64];   // 32 KB
    __shared__ ushort_t Bs[2][128 * 64];   // 32 KB
    const int tid  = threadIdx.x;
    const int lane = tid & 63;
    const int w    = tid >> 6;        // wave 0..3
    const int wm   = w >> 1, wn = w & 1;
    const int m0 = blockIdx.y * 128, n0 = blockIdx.x * 128;

    const int scol = ((lane & 7) ^ (lane >> 3)) * 8;
    const ushort_t* ap[4];
    const ushort_t* bp[4];
    int ldsoff[4];
#pragma unroll
    for (int i = 0; i < 4; ++i) {
        const int r = w * 32 + i * 8 + (lane >> 3);
        const int gm = min(m0 + r, M - 1);                // clamp tail tile
        ap[i] = A + (size_t)gm * lda + scol;
        bp[i] = B + (size_t)(n0 + r) * ldb + scol;        // n0+r < N always
        ldsoff[i] = (w * 32 + i * 8) * 64 + lane * 8;
    }

    f32x4 acc[4][4] = {};

    const int nt = K >> 6;   // K/64 tiles
#pragma unroll
    for (int i = 0; i < 4; ++i) {
        async16(&As[0][ldsoff[i]], ap[i]);
        async16(&Bs[0][ldsoff[i]], bp[i]);
    }
    __syncthreads();   // vmcnt(0) drain -> buf0 ready

    const int fr = lane & 15, fk8 = lane >> 4;   // fragment row, k-chunk 0..3
    const int key = fr & 7;                      // read-side swizzle key

    for (int t = 0; t < nt; ++t) {
        const int cur = t & 1;
        if (t + 1 < nt) {   // issue next-tile loads FIRST (overlap with compute)
            const int ko = (t + 1) << 6;
#pragma unroll
            for (int i = 0; i < 4; ++i) {
                async16(&As[cur ^ 1][ldsoff[i]], ap[i] + ko);
                async16(&Bs[cur ^ 1][ldsoff[i]], bp[i] + ko);
            }
        }
#pragma unroll
        for (int ks = 0; ks < 2; ++ks) {         // two 32-K subtiles
            const int pc = ((ks * 4 + fk8) ^ key) * 8;   // swizzled chunk offset
            b16x8 af[4], bg[4];
#pragma unroll
            for (int m = 0; m < 4; ++m)
                af[m] = *reinterpret_cast<const b16x8*>(
                    &As[cur][(wm * 64 + m * 16 + fr) * 64 + pc]);
#pragma unroll
            for (int n = 0; n < 4; ++n)
                bg[n] = *reinterpret_cast<const b16x8*>(
                    &Bs[cur][(wn * 64 + n * 16 + fr) * 64 + pc]);
#pragma unroll
            for (int m = 0; m < 4; ++m)
#pragma unroll
                for (int n = 0; n < 4; ++n)
                    acc[m][n] = __builtin_amdgcn_mfma_f32_16x16x32_bf16(
                        bg[n], af[m], acc[m][n], 0, 0, 0);   // swapped -> C^T
        }
        __syncthreads();   // drains vmcnt (prefetch landed) + seals buf reads
    }

    // epilogue (transposed frag): row = ...+ma*16+fr ; cols = ...+nb*16+fq*4+{0..3}
    const int fq = lane >> 4;
    const int h = (n0 >> 6) + wn;           // head (SCORES mode; 64-col blocks)
    ushort_t* Cb = (ushort_t*)Cv;
    float*    Cf = (float*)Cv;

#pragma unroll
    for (int ma = 0; ma < 4; ++ma) {
        const int row = m0 + wm * 64 + ma * 16 + fr;
        const bool rowok = row < M;
        float pa = 0.f, pb = 0.f;
#pragma unroll
        for (int nb = 0; nb < 4; ++nb) {
            const int col0 = n0 + wn * 64 + nb * 16 + fq * 4;
            float v[4];
#pragma unroll
            for (int r = 0; r < 4; ++r) v[r] = acc[ma][nb][r];
            if (bias) {
                const float4 bb = *reinterpret_cast<const float4*>(&bias[col0]);
                v[0] += bb.x; v[1] += bb.y; v[2] += bb.z; v[3] += bb.w;
            }
            if (RELU) {
#pragma unroll
                for (int r = 0; r < 4; ++r) v[r] = fmaxf(v[r], 0.f);
            }
            if constexpr (SCORES) {
                const int d0 = nb * 16 + fq * 4;   // dim within head
#pragma unroll
                for (int r = 0; r < 4; ++r) {
                    pa = fmaf(v[r], al[h * HD + d0 + r], pa);
                    pb = fmaf(v[r], ar[h * HD + d0 + r], pb);
                }
            }
            if (rowok) {
                if constexpr (OUT_BF16) {
                    ushort4 u = make_ushort4(f2bf(v[0]), f2bf(v[1]), f2bf(v[2]), f2bf(v[3]));
                    *reinterpret_cast<ushort4*>(&Cb[(size_t)row * ldc + col0]) = u;
                } else {
                    float4* cp = reinterpret_cast<float4*>(&Cf[(size_t)row * ldc + col0]);
                    if (ACCUM) {
                        float4 o = *cp;
                        o.x += v[0]; o.y += v[1]; o.z += v[2]; o.w += v[3];
                        *cp = o;
                    } else {
                        *cp = make_float4(v[0], v[1], v[2], v[3]);
                    }
                }
            }
        }
        if constexpr (SCORES) {
            pa += __shfl_xor(pa, 16); pa += __shfl_xor(pa, 32);
            pb += __shfl_xor(pb, 16); pb += __shfl_xor(pb, 32);
            if (fq == 0 && rowok) {
                SS[row * HEADS + h] = pa;
                SD[row * HEADS + h] = pb;
            }
        }
    }
}

// ---------------------------------------------------------------------------
// fp32 -> bf16 conversion, 4 elems/thread (n % 4 == 0)
// ---------------------------------------------------------------------------
__global__ void f2b_kernel(const float* __restrict__ x, ushort_t* __restrict__ y, int n)
{
    int i = (blockIdx.x * 256 + threadIdx.x) * 4;
    if (i >= n) return;
    const float4 v = *reinterpret_cast<const float4*>(&x[i]);
    ushort2 a = make_ushort2(f2bf(v.x), f2bf(v.y));
    ushort2 b = make_ushort2(f2bf(v.z), f2bf(v.w));
    *reinterpret_cast<ushort2*>(&y[i])     = a;
    *reinterpret_cast<ushort2*>(&y[i + 2]) = b;
}

// feats -> H (fp32 copy) + Hb (bf16), one pass
__global__ void feats_init(const float* __restrict__ x, float* __restrict__ H,
                           ushort_t* __restrict__ Hb, int n)
{
    int i = (blockIdx.x * 256 + threadIdx.x) * 4;
    if (i >= n) return;
    const float4 v = *reinterpret_cast<const float4*>(&x[i]);
    *reinterpret_cast<float4*>(&H[i]) = v;
    *reinterpret_cast<ushort4*>(&Hb[i]) =
        make_ushort4(f2bf(v.x), f2bf(v.y), f2bf(v.z), f2bf(v.w));
}

// Repack Wh[h][f][d] (one prop step) -> Wp[col][f] bf16, col = h*64+d
__global__ void repack_wb(const float* __restrict__ Wh, ushort_t* __restrict__ Wp)
{
    int idx = blockIdx.x * 256 + threadIdx.x;
    if (idx >= NHID * NHID) return;
    int col = idx >> 9, f = idx & 511;
    int h = col >> 6, d = col & 63;
    Wp[idx] = f2bf(Wh[((size_t)h * NHID + f) * HD + d]);
}

// ---------------------------------------------------------------------------
// CSR build
// ---------------------------------------------------------------------------
__global__ void count_deg(const int* __restrict__ dst, int* __restrict__ deg)
{
    int e = blockIdx.x * 256 + threadIdx.x;
    if (e < NE) atomicAdd(&deg[dst[e]], 1);
}

__global__ __launch_bounds__(1024)
void scan_deg(const int* __restrict__ deg, int* __restrict__ rowptr)
{
    __shared__ int part[1024];
    const int tid = threadIdx.x;
    const int per = (NN + 1023) / 1024;
    const int start = tid * per;
    int s = 0;
    for (int j = 0; j < per; ++j)
        if (start + j < NN) s += deg[start + j];
    part[tid] = s;
    __syncthreads();
    for (int off = 1; off < 1024; off <<= 1) {
        int v = (tid >= off) ? part[tid - off] : 0;
        __syncthreads();
        part[tid] += v;
        __syncthreads();
    }
    int prefix = (tid == 0) ? 0 : part[tid - 1];
    for (int j = 0; j < per; ++j) {
        if (start + j < NN) {
            rowptr[start + j] = prefix;
            prefix += deg[start + j];
        }
    }
    if (tid == 1023) rowptr[NN] = part[1023];
}

__global__ void copy_int(const int* __restrict__ a, int* __restrict__ b, int n)
{
    int i = blockIdx.x * 256 + threadIdx.x;
    if (i < n) b[i] = a[i];
}

__global__ void scatter_edges(const int* __restrict__ src, const int* __restrict__ dst,
                              int* __restrict__ cursor, int* __restrict__ csrc)
{
    int e = blockIdx.x * 256 + threadIdx.x;
    if (e < NE) {
        int p = atomicAdd(&cursor[dst[e]], 1);
        csrc[p] = src[e];
    }
}

// ---------------------------------------------------------------------------
// Per-dst-node online segment-softmax + aggregation, fused ELU + residual.
// ROUND-16: optional gather mode. gl == nullptr: n = blockIdx.x, in-place
// H/Hb update (round-11 verified behavior). gl != nullptr (last prop step):
// n = gl[blockIdx.x]; H is READ-ONLY (duplicate indices in gl would race an
// in-place update); results go to row blockIdx.x of Gf (fp32) / Gb (bf16) —
// duplicates write identical rows to distinct slots.
// ---------------------------------------------------------------------------
__global__ __launch_bounds__(256)
void gat_aggregate(const ushort_t* __restrict__ Zb, const float* __restrict__ SS,
                   const float* __restrict__ SD, const int* __restrict__ rowptr,
                   const int* __restrict__ csrc, const int* __restrict__ gl,
                   const float* __restrict__ Hin, float* __restrict__ Gf,
                   ushort_t* __restrict__ Gb)
{
    const int bi = blockIdx.x;
    const int n  = gl ? gl[bi] : bi;
    const int tid = threadIdx.x;
    __shared__ float sdst_sh[8];
    __shared__ float v_sh[128 * 9];   // [j][h], stride 9 -> conflict-free
    __shared__ int   src_sh[128];

    const int rp0 = rowptr[n];
    const int deg = rowptr[n + 1] - rp0;

    if (tid < 8) sdst_sh[tid] = SD[n * HEADS + tid];
    __syncthreads();

    const int g32 = tid & 31;      // lane within head group
    const int h   = tid >> 5;      // head 0..7 (== (tid*2)>>6)
    const int d0  = tid * 2;       // this thread's two output dims
    float m_run = -1e30f, s_run = 0.f;
    float accx = 0.f, accy = 0.f;

    for (int base = 0; base < deg; base += 128) {
        const int cnt = min(128, deg - base);
        // A: gather scores ONCE into LDS (leaky-relu applied)
        for (int idx = tid; idx < cnt * 8; idx += 256) {
            const int j = idx >> 3, hh = idx & 7;
            const int s = csrc[rp0 + base + j];
            if (hh == 0) src_sh[j] = s;
            const float x = SS[s * HEADS + hh] + sdst_sh[hh];
            v_sh[j * 9 + hh] = x > 0.f ? x : 0.01f * x;
        }
        __syncthreads();
        // B: per-head chunk max -> exp -> sum
        float cm = -1e30f;
#pragma unroll
        for (int k = 0; k < 4; ++k) {
            const int j = g32 + k * 32;
            if (j < cnt) cm = fmaxf(cm, v_sh[j * 9 + h]);
        }
#pragma unroll
        for (int off = 1; off < 32; off <<= 1) cm = fmaxf(cm, __shfl_xor(cm, off));
        const float m_new = fmaxf(m_run, cm);
        const float f = expf(m_run - m_new);
        float ps = 0.f;
#pragma unroll
        for (int k = 0; k < 4; ++k) {
            const int j = g32 + k * 32;
            if (j < cnt) {
                const float e = expf(v_sh[j * 9 + h] - m_new);
                v_sh[j * 9 + h] = e;
                ps += e;
            }
        }
#pragma unroll
        for (int off = 1; off < 32; off <<= 1) ps += __shfl_xor(ps, off);
        s_run = s_run * f + ps;
        m_run = m_new;
        accx *= f; accy *= f;
        __syncthreads();
        // C: accumulate unnormalized alpha * z — unroll 8 for MLP
        int j = 0;
        for (; j + 8 <= cnt; j += 8) {
            int   sv[8];
            float av[8];
            ushort2 zv[8];
#pragma unroll
            for (int u = 0; u < 8; ++u) {
                sv[u] = src_sh[j + u];
                av[u] = v_sh[(j + u) * 9 + h];
            }
#pragma unroll
            for (int u = 0; u < 8; ++u)
                zv[u] = *reinterpret_cast<const ushort2*>(&Zb[(size_t)sv[u] * NHID + d0]);
#pragma unroll
            for (int u = 0; u < 8; ++u) {
                accx = fmaf(av[u], bf2f(zv[u].x), accx);
                accy = fmaf(av[u], bf2f(zv[u].y), accy);
            }
        }
        for (; j < cnt; ++j) {
            const int s = src_sh[j];
            const float a = v_sh[j * 9 + h];
            const ushort2 zv = *reinterpret_cast<const ushort2*>(&Zb[(size_t)s * NHID + d0]);
            accx = fmaf(a, bf2f(zv.x), accx);
            accy = fmaf(a, bf2f(zv.y), accy);
        }
        __syncthreads();
    }

    const float inv = deg > 0 ? 1.f / s_run : 0.f;
    accx *= inv; accy *= inv;

    const size_t oin  = (size_t)n * NHID + d0;
    const size_t oout = (size_t)bi * NHID + d0;   // == oin when gl == nullptr
    const float2 hv = *reinterpret_cast<const float2*>(&Hin[oin]);
    const float ex = accx > 0.f ? accx : expm1f(accx);
    const float ey = accy > 0.f ? accy : expm1f(accy);
    const float rx = ex + hv.x, ry = ey + hv.y;
    *reinterpret_cast<float2*>(&Gf[oout]) = make_float2(rx, ry);
    *reinterpret_cast<ushort2*>(&Gb[oout]) = make_ushort2(f2bf(rx), f2bf(ry));
}

// ---------------------------------------------------------------------------
// LN( Y + b2 + R ) * g + b  -> Hf (fp32) and optionally Hb (bf16)
// one wave per row; lane owns 8 CONSECUTIVE elems (float4 x2 loads/stores)
// ---------------------------------------------------------------------------
__global__ __launch_bounds__(256)
void ffn_ln(const float* __restrict__ Y, const float* __restrict__ b2,
            const float* __restrict__ gw, const float* __restrict__ bw,
            const float* __restrict__ R, float* __restrict__ Hf,
            ushort_t* __restrict__ Hb, int M)
{
    const int wave = threadIdx.x >> 6, lane = threadIdx.x & 63;
    const int n = blockIdx.x * 4 + wave;
    if (n >= M) return;
    const int f0 = lane * 8;
    const size_t o = (size_t)n * NHID + f0;

    const float4 ya = *reinterpret_cast<const float4*>(&Y[o]);
    const float4 yb = *reinterpret_cast<const float4*>(&Y[o + 4]);
    const float4 ha = *reinterpret_cast<const float4*>(&R[o]);
    const float4 hb = *reinterpret_cast<const float4*>(&R[o + 4]);
    const float4 ba = *reinterpret_cast<const float4*>(&b2[f0]);
    const float4 bb = *reinterpret_cast<const float4*>(&b2[f0 + 4]);

    float v[8] = { ya.x + ba.x + ha.x, ya.y + ba.y + ha.y,
                   ya.z + ba.z + ha.z, ya.w + ba.w + ha.w,
                   yb.x + bb.x + hb.x, yb.y + bb.y + hb.y,
                   yb.z + bb.z + hb.z, yb.w + bb.w + hb.w };
    float sum = 0.f;
#pragma unroll
    for (int k = 0; k < 8; ++k) sum += v[k];
#pragma unroll
    for (int off = 1; off < 64; off <<= 1) sum += __shfl_xor(sum, off);
    const float mu = sum * (1.f / NHID);
    float var = 0.f;
#pragma unroll
    for (int k = 0; k < 8; ++k) { const float d = v[k] - mu; var = fmaf(d, d, var); }
#pragma unroll
    for (int off = 1; off < 64; off <<= 1) var += __shfl_xor(var, off);
    var *= (1.f / NHID);
    const float inv = rsqrtf(var + LN_EPS);

    const float4 ga = *reinterpret_cast<const float4*>(&gw[f0]);
    const float4 gb = *reinterpret_cast<const float4*>(&gw[f0 + 4]);
    const float4 wa = *reinterpret_cast<const float4*>(&bw[f0]);
    const float4 wb = *reinterpret_cast<const float4*>(&bw[f0 + 4]);
    const float gg[8] = { ga.x, ga.y, ga.z, ga.w, gb.x, gb.y, gb.z, gb.w };
    const float ww[8] = { wa.x, wa.y, wa.z, wa.w, wb.x, wb.y, wb.z, wb.w };

    float r[8];
#pragma unroll
    for (int k = 0; k < 8; ++k) r[k] = (v[k] - mu) * inv * gg[k] + ww[k];

    *reinterpret_cast<float4*>(&Hf[o])     = make_float4(r[0], r[1], r[2], r[3]);
    *reinterpret_cast<float4*>(&Hf[o + 4]) = make_float4(r[4], r[5], r[6], r[7]);
    if (Hb) {
        *reinterpret_cast<ushort4*>(&Hb[o])     = make_ushort4(f2bf(r[0]), f2bf(r[1]), f2bf(r[2]), f2bf(r[3]));
        *reinterpret_cast<ushort4*>(&Hb[o + 4]) = make_ushort4(f2bf(r[4]), f2bf(r[5]), f2bf(r[6]), f2bf(r[7]));
    }
}

// ---------------------------------------------------------------------------
extern "C" void kernel_launch(void* const* d_in, const int* in_sizes, int n_in,
                              void* d_out, int out_size, void* d_ws, size_t ws_size,
                              hipStream_t stream)
{
    const float* feats = (const float*)d_in[0];
    const float* Wh    = (const float*)d_in[1];
    const float* al    = (const float*)d_in[2];
    const float* ar    = (const float*)d_in[3];
    const float* w1    = (const float*)d_in[4];
    const float* b1    = (const float*)d_in[5];
    const float* w2    = (const float*)d_in[6];
    const float* b2    = (const float*)d_in[7];
    const float* ln_g  = (const float*)d_in[8];
    const float* ln_b  = (const float*)d_in[9];
    const int* esrc    = (const int*)d_in[10];
    const int* edst    = (const int*)d_in[11];
    const int* sent    = (const int*)d_in[12];
    float* out = (float*)d_out;

    char* ws = (char*)d_ws;
    size_t off = 0;
    auto alloc = [&](size_t bytes) -> void* {
        void* p = ws + off;
        off = (off + bytes + 255) & ~(size_t)255;
        return p;
    };
    float*    H   = (float*)alloc((size_t)NN * NHID * 4);
    float*    Y   = (float*)alloc((size_t)NN * NHID * 4);   // FFN output (fp32)
    ushort_t* Hb  = (ushort_t*)alloc((size_t)NN * NHID * 2);
    ushort_t* Zb  = (ushort_t*)alloc((size_t)NN * NHID * 2);
    float*    Gf  = (float*)alloc((size_t)NS * NHID * 4);   // gathered post-GAT (p=1)
    ushort_t* Gb  = (ushort_t*)alloc((size_t)NS * NHID * 2);
    float*    SS  = (float*)alloc((size_t)NN * HEADS * 4);
    float*    SD  = (float*)alloc((size_t)NN * HEADS * 4);
    ushort_t* Wpb = (ushort_t*)alloc((size_t)NHID * NHID * 2);
    ushort_t* w1b = (ushort_t*)alloc((size_t)FH * NHID * 2);
    ushort_t* w2b = (ushort_t*)alloc((size_t)NHID * FH * 2);
    int* rowptr = (int*)alloc((NN + 1) * 4);
    int* deg    = (int*)alloc(NN * 4);
    int* cursor = (int*)alloc(NN * 4);
    int* csrc   = (int*)alloc((size_t)NE * 4);
    // FFN mid chunk (bf16): as large as remaining workspace allows
    int CH = FH;
    while (CH > 128 && off + (size_t)NN * CH * 2 > ws_size) CH >>= 1;
    ushort_t* MIDb = (ushort_t*)alloc((size_t)NN * CH * 2);

    // ---- CSR build ----
    hipMemsetAsync(deg, 0, NN * 4, stream);
    count_deg<<<(NE + 255) / 256, 256, 0, stream>>>(edst, deg);
    scan_deg<<<1, 1024, 0, stream>>>(deg, rowptr);
    copy_int<<<(NN + 255) / 256, 256, 0, stream>>>(rowptr, cursor, NN);
    scatter_edges<<<(NE + 255) / 256, 256, 0, stream>>>(esrc, edst, cursor, csrc);

    // ---- weights -> bf16 (once) ----
    f2b_kernel<<<(FH * NHID / 4 + 255) / 256, 256, 0, stream>>>(w1, w1b, FH * NHID);
    f2b_kernel<<<(NHID * FH / 4 + 255) / 256, 256, 0, stream>>>(w2, w2b, NHID * FH);

    // ---- h = feats (fp32 master + bf16 copy, one pass) ----
    feats_init<<<(NN * NHID / 4 + 255) / 256, 256, 0, stream>>>(feats, H, Hb, NN * NHID);

    const int MT  = (NN + 127) / 128;   // 157 m-tiles (full)
    const int MTs = (NS + 127) / 128;   // 16 m-tiles (sent rows)
    for (int p = 0; p < 2; ++p) {
        // z = h @ Wh[p]  (bf16 MFMA, bf16 out) + fused attention scores (ALL nodes)
        repack_wb<<<(NHID * NHID + 255) / 256, 256, 0, stream>>>(
            Wh + (size_t)p * HEADS * NHID * HD, Wpb);
        mfma_gemm_nt<0, 0, 1, 1><<<dim3(NHID / 128, MT), 256, 0, stream>>>(
            Hb, Wpb, Zb, nullptr,
            al + (size_t)p * HEADS * HD, ar + (size_t)p * HEADS * HD, SS, SD,
            NN, NHID, NHID, NHID, NHID, NHID);

        if (p == 0) {
            // full aggregate (in place) + full FFN
            gat_aggregate<<<NN, 256, 0, stream>>>(
                Zb, SS, SD, rowptr, csrc, nullptr, H, H, Hb);
            for (int c0 = 0; c0 < FH; c0 += CH) {
                mfma_gemm_nt<1, 0, 1, 0><<<dim3(CH / 128, MT), 256, 0, stream>>>(
                    Hb, w1b + (size_t)c0 * NHID, MIDb, b1 + c0,
                    nullptr, nullptr, nullptr, nullptr,
                    NN, CH, NHID, NHID, NHID, CH);
                if (c0 == 0)
                    mfma_gemm_nt<0, 0, 0, 0><<<dim3(NHID / 128, MT), 256, 0, stream>>>(
                        MIDb, w2b + c0, Y, nullptr,
                        nullptr, nullptr, nullptr, nullptr,
                        NN, NHID, CH, CH, FH, NHID);
                else
                    mfma_gemm_nt<0, 1, 0, 0><<<dim3(NHID / 128, MT), 256, 0, stream>>>(
                        MIDb, w2b + c0, Y, nullptr,
                        nullptr, nullptr, nullptr, nullptr,
                        NN, NHID, CH, CH, FH, NHID);
            }
            ffn_ln<<<(NN + 3) / 4, 256, 0, stream>>>(
                Y, b2, ln_g, ln_b, H, H, Hb, NN);
        } else {
            // LAST prop step: everything after aggregation is row-wise and only
            // sent rows are read -> aggregate only sent dst rows (gather mode,
            // H read-only; duplicate-safe) and run FFN+LN at M = NS, writing
            // the final LN result directly to out.
            gat_aggregate<<<NS, 256, 0, stream>>>(
                Zb, SS, SD, rowptr, csrc, sent, H, Gf, Gb);
            for (int c0 = 0; c0 < FH; c0 += CH) {
                mfma_gemm_nt<1, 0, 1, 0><<<dim3(CH / 128, MTs), 256, 0, stream>>>(
                    Gb, w1b + (size_t)c0 * NHID, MIDb, b1 + c0,
                    nullptr, nullptr, nullptr, nullptr,
                    NS, CH, NHID, NHID, NHID, CH);
                if (c0 == 0)
                    mfma_gemm_nt<0, 0, 0, 0><<<dim3(NHID / 128, MTs), 256, 0, stream>>>(
                        MIDb, w2b + c0, Y, nullptr,
                        nullptr, nullptr, nullptr, nullptr,
                        NS, NHID, CH, CH, FH, NHID);
                else
                    mfma_gemm_nt<0, 1, 0, 0><<<dim3(NHID / 128, MTs), 256, 0, stream>>>(
                        MIDb, w2b + c0, Y, nullptr,
                        nullptr, nullptr, nullptr, nullptr,
                        NS, NHID, CH, CH, FH, NHID);
            }
            ffn_ln<<<(NS + 3) / 4, 256, 0, stream>>>(
                Y, b2, ln_g, ln_b, Gf, out, nullptr, NS);
        }
    }
}

// Round 17
// 475.358 us; speedup vs baseline: 1.4753x; 1.0211x over previous
//
#include <hip/hip_runtime.h>
#include <hip/hip_bf16.h>
#include <cmath>

// Problem constants (match reference)
#define NN   20000     // nodes
#define NE   400000    // edges
#define NHID 512
#define HEADS 8
#define HD   64
#define FH   2048
#define NS   2000
#define LN_EPS 1e-5f

typedef unsigned short ushort_t;
typedef __bf16 b16x8 __attribute__((ext_vector_type(8)));
typedef float  f32x4 __attribute__((ext_vector_type(4)));

__device__ __forceinline__ ushort_t f2bf(float f) {
    unsigned u = __builtin_bit_cast(unsigned, f);
    unsigned r = (u + 0x7FFFu + ((u >> 16) & 1u)) >> 16;   // RNE
    return (ushort_t)r;
}
__device__ __forceinline__ float bf2f(ushort_t u) {
    return __builtin_bit_cast(float, (unsigned)u << 16);
}

__device__ __forceinline__ void async16(ushort_t* lds, const ushort_t* g) {
    __builtin_amdgcn_global_load_lds(
        (const __attribute__((address_space(1))) void*)g,
        (__attribute__((address_space(3))) void*)lds,
        16, 0, 0);
}

// ---------------------------------------------------------------------------
// 128x128 bf16 MFMA GEMM (round-12 champion form, BK=64, 2-phase, swizzled).
// ROUND-17: XCD-aware block swizzle (T1, bijective m204 variant). Default
// dispatch round-robins XCD by (m*16+n)%8 = n%8 -> every m-tile's A-panel is
// pulled into ALL 8 XCD L2s (FETCH = 4x compulsory). The chunked bijection
// gives each XCD a contiguous run of linear ids (m-major) -> each A-panel
// resident in exactly one L2. Pure blockIdx permutation: zero correctness
// impact.
// ---------------------------------------------------------------------------
template<int RELU, int ACCUM, int OUT_BF16, int SCORES>
__global__ __launch_bounds__(256)
void mfma_gemm_nt(const ushort_t* __restrict__ A, const ushort_t* __restrict__ B,
                  void* __restrict__ Cv, const float* __restrict__ bias,
                  const float* __restrict__ al, const float* __restrict__ ar,
                  float* __restrict__ SS, float* __restrict__ SD,
                  int M, int N, int K, int lda, int ldb, int ldc)
{
    __shared__ ushort_t As[2][128 * 64];   // 32 KB
    __shared__ ushort_t Bs[2][128 * 64];   // 32 KB
    const int tid  = threadIdx.x;
    const int lane = tid & 63;
    const int w    = tid >> 6;        // wave 0..3
    const int wm   = w >> 1, wn = w & 1;

    // T1: bijective XCD-chunked remap of the flattened block id.
    const int nwg = (int)(gridDim.x * gridDim.y);
    int lin = (int)(blockIdx.y * gridDim.x + blockIdx.x);
    {
        const int q = nwg >> 3, r = nwg & 7;
        const int xcd = lin & 7, idx = lin >> 3;
        lin = (xcd < r ? xcd * (q + 1) : r * (q + 1) + (xcd - r) * q) + idx;
    }
    const int bx = lin % (int)gridDim.x;
    const int by = lin / (int)gridDim.x;
    const int m0 = by * 128, n0 = bx * 128;

    const int scol = ((lane & 7) ^ (lane >> 3)) * 8;
    const ushort_t* ap[4];
    const ushort_t* bp[4];
    int ldsoff[4];
#pragma unroll
    for (int i = 0; i < 4; ++i) {
        const int r = w * 32 + i * 8 + (lane >> 3);
        const int gm = min(m0 + r, M - 1);                // clamp tail tile
        ap[i] = A + (size_t)gm * lda + scol;
        bp[i] = B + (size_t)(n0 + r) * ldb + scol;        // n0+r < N always
        ldsoff[i] = (w * 32 + i * 8) * 64 + lane * 8;
    }

    f32x4 acc[4][4] = {};

    const int nt = K >> 6;   // K/64 tiles
#pragma unroll
    for (int i = 0; i < 4; ++i) {
        async16(&As[0][ldsoff[i]], ap[i]);
        async16(&Bs[0][ldsoff[i]], bp[i]);
    }
    __syncthreads();   // vmcnt(0) drain -> buf0 ready

    const int fr = lane & 15, fk8 = lane >> 4;   // fragment row, k-chunk 0..3
    const int key = fr & 7;                      // read-side swizzle key

    for (int t = 0; t < nt; ++t) {
        const int cur = t & 1;
        if (t + 1 < nt) {   // issue next-tile loads FIRST (overlap with compute)
            const int ko = (t + 1) << 6;
#pragma unroll
            for (int i = 0; i < 4; ++i) {
                async16(&As[cur ^ 1][ldsoff[i]], ap[i] + ko);
                async16(&Bs[cur ^ 1][ldsoff[i]], bp[i] + ko);
            }
        }
#pragma unroll
        for (int ks = 0; ks < 2; ++ks) {         // two 32-K subtiles
            const int pc = ((ks * 4 + fk8) ^ key) * 8;   // swizzled chunk offset
            b16x8 af[4], bg[4];
#pragma unroll
            for (int m = 0; m < 4; ++m)
                af[m] = *reinterpret_cast<const b16x8*>(
                    &As[cur][(wm * 64 + m * 16 + fr) * 64 + pc]);
#pragma unroll
            for (int n = 0; n < 4; ++n)
                bg[n] = *reinterpret_cast<const b16x8*>(
                    &Bs[cur][(wn * 64 + n * 16 + fr) * 64 + pc]);
#pragma unroll
            for (int m = 0; m < 4; ++m)
#pragma unroll
                for (int n = 0; n < 4; ++n)
                    acc[m][n] = __builtin_amdgcn_mfma_f32_16x16x32_bf16(
                        bg[n], af[m], acc[m][n], 0, 0, 0);   // swapped -> C^T
        }
        __syncthreads();   // drains vmcnt (prefetch landed) + seals buf reads
    }

    // epilogue (transposed frag): row = ...+ma*16+fr ; cols = ...+nb*16+fq*4+{0..3}
    const int fq = lane >> 4;
    const int h = (n0 >> 6) + wn;           // head (SCORES mode; 64-col blocks)
    ushort_t* Cb = (ushort_t*)Cv;
    float*    Cf = (float*)Cv;

#pragma unroll
    for (int ma = 0; ma < 4; ++ma) {
        const int row = m0 + wm * 64 + ma * 16 + fr;
        const bool rowok = row < M;
        float pa = 0.f, pb = 0.f;
#pragma unroll
        for (int nb = 0; nb < 4; ++nb) {
            const int col0 = n0 + wn * 64 + nb * 16 + fq * 4;
            float v[4];
#pragma unroll
            for (int r = 0; r < 4; ++r) v[r] = acc[ma][nb][r];
            if (bias) {
                const float4 bb = *reinterpret_cast<const float4*>(&bias[col0]);
                v[0] += bb.x; v[1] += bb.y; v[2] += bb.z; v[3] += bb.w;
            }
            if (RELU) {
#pragma unroll
                for (int r = 0; r < 4; ++r) v[r] = fmaxf(v[r], 0.f);
            }
            if constexpr (SCORES) {
                const int d0 = nb * 16 + fq * 4;   // dim within head
#pragma unroll
                for (int r = 0; r < 4; ++r) {
                    pa = fmaf(v[r], al[h * HD + d0 + r], pa);
                    pb = fmaf(v[r], ar[h * HD + d0 + r], pb);
                }
            }
            if (rowok) {
                if constexpr (OUT_BF16) {
                    ushort4 u = make_ushort4(f2bf(v[0]), f2bf(v[1]), f2bf(v[2]), f2bf(v[3]));
                    *reinterpret_cast<ushort4*>(&Cb[(size_t)row * ldc + col0]) = u;
                } else {
                    float4* cp = reinterpret_cast<float4*>(&Cf[(size_t)row * ldc + col0]);
                    if (ACCUM) {
                        float4 o = *cp;
                        o.x += v[0]; o.y += v[1]; o.z += v[2]; o.w += v[3];
                        *cp = o;
                    } else {
                        *cp = make_float4(v[0], v[1], v[2], v[3]);
                    }
                }
            }
        }
        if constexpr (SCORES) {
            pa += __shfl_xor(pa, 16); pa += __shfl_xor(pa, 32);
            pb += __shfl_xor(pb, 16); pb += __shfl_xor(pb, 32);
            if (fq == 0 && rowok) {
                SS[row * HEADS + h] = pa;
                SD[row * HEADS + h] = pb;
            }
        }
    }
}

// ---------------------------------------------------------------------------
// fp32 -> bf16 conversion, 4 elems/thread (n % 4 == 0)
// ---------------------------------------------------------------------------
__global__ void f2b_kernel(const float* __restrict__ x, ushort_t* __restrict__ y, int n)
{
    int i = (blockIdx.x * 256 + threadIdx.x) * 4;
    if (i >= n) return;
    const float4 v = *reinterpret_cast<const float4*>(&x[i]);
    ushort2 a = make_ushort2(f2bf(v.x), f2bf(v.y));
    ushort2 b = make_ushort2(f2bf(v.z), f2bf(v.w));
    *reinterpret_cast<ushort2*>(&y[i])     = a;
    *reinterpret_cast<ushort2*>(&y[i + 2]) = b;
}

// feats -> H (fp32 copy) + Hb (bf16), one pass
__global__ void feats_init(const float* __restrict__ x, float* __restrict__ H,
                           ushort_t* __restrict__ Hb, int n)
{
    int i = (blockIdx.x * 256 + threadIdx.x) * 4;
    if (i >= n) return;
    const float4 v = *reinterpret_cast<const float4*>(&x[i]);
    *reinterpret_cast<float4*>(&H[i]) = v;
    *reinterpret_cast<ushort4*>(&Hb[i]) =
        make_ushort4(f2bf(v.x), f2bf(v.y), f2bf(v.z), f2bf(v.w));
}

// Repack Wh[h][f][d] (one prop step) -> Wp[col][f] bf16, col = h*64+d
__global__ void repack_wb(const float* __restrict__ Wh, ushort_t* __restrict__ Wp)
{
    int idx = blockIdx.x * 256 + threadIdx.x;
    if (idx >= NHID * NHID) return;
    int col = idx >> 9, f = idx & 511;
    int h = col >> 6, d = col & 63;
    Wp[idx] = f2bf(Wh[((size_t)h * NHID + f) * HD + d]);
}

// ---------------------------------------------------------------------------
// CSR build
// ---------------------------------------------------------------------------
__global__ void count_deg(const int* __restrict__ dst, int* __restrict__ deg)
{
    int e = blockIdx.x * 256 + threadIdx.x;
    if (e < NE) atomicAdd(&deg[dst[e]], 1);
}

__global__ __launch_bounds__(1024)
void scan_deg(const int* __restrict__ deg, int* __restrict__ rowptr)
{
    __shared__ int part[1024];
    const int tid = threadIdx.x;
    const int per = (NN + 1023) / 1024;
    const int start = tid * per;
    int s = 0;
    for (int j = 0; j < per; ++j)
        if (start + j < NN) s += deg[start + j];
    part[tid] = s;
    __syncthreads();
    for (int off = 1; off < 1024; off <<= 1) {
        int v = (tid >= off) ? part[tid - off] : 0;
        __syncthreads();
        part[tid] += v;
        __syncthreads();
    }
    int prefix = (tid == 0) ? 0 : part[tid - 1];
    for (int j = 0; j < per; ++j) {
        if (start + j < NN) {
            rowptr[start + j] = prefix;
            prefix += deg[start + j];
        }
    }
    if (tid == 1023) rowptr[NN] = part[1023];
}

__global__ void copy_int(const int* __restrict__ a, int* __restrict__ b, int n)
{
    int i = blockIdx.x * 256 + threadIdx.x;
    if (i < n) b[i] = a[i];
}

__global__ void scatter_edges(const int* __restrict__ src, const int* __restrict__ dst,
                              int* __restrict__ cursor, int* __restrict__ csrc)
{
    int e = blockIdx.x * 256 + threadIdx.x;
    if (e < NE) {
        int p = atomicAdd(&cursor[dst[e]], 1);
        csrc[p] = src[e];
    }
}

// ---------------------------------------------------------------------------
// Per-dst-node online segment-softmax + aggregation, fused ELU + residual.
// gl == nullptr: in-place update (n = blockIdx.x). gl != nullptr: gather
// mode for the last prop step — H read-only (duplicate-safe), row blockIdx.x
// of Gf/Gb written.
// ---------------------------------------------------------------------------
__global__ __launch_bounds__(256)
void gat_aggregate(const ushort_t* __restrict__ Zb, const float* __restrict__ SS,
                   const float* __restrict__ SD, const int* __restrict__ rowptr,
                   const int* __restrict__ csrc, const int* __restrict__ gl,
                   const float* __restrict__ Hin, float* __restrict__ Gf,
                   ushort_t* __restrict__ Gb)
{
    const int bi = blockIdx.x;
    const int n  = gl ? gl[bi] : bi;
    const int tid = threadIdx.x;
    __shared__ float sdst_sh[8];
    __shared__ float v_sh[128 * 9];   // [j][h], stride 9 -> conflict-free
    __shared__ int   src_sh[128];

    const int rp0 = rowptr[n];
    const int deg = rowptr[n + 1] - rp0;

    if (tid < 8) sdst_sh[tid] = SD[n * HEADS + tid];
    __syncthreads();

    const int g32 = tid & 31;      // lane within head group
    const int h   = tid >> 5;      // head 0..7 (== (tid*2)>>6)
    const int d0  = tid * 2;       // this thread's two output dims
    float m_run = -1e30f, s_run = 0.f;
    float accx = 0.f, accy = 0.f;

    for (int base = 0; base < deg; base += 128) {
        const int cnt = min(128, deg - base);
        // A: gather scores ONCE into LDS (leaky-relu applied)
        for (int idx = tid; idx < cnt * 8; idx += 256) {
            const int j = idx >> 3, hh = idx & 7;
            const int s = csrc[rp0 + base + j];
            if (hh == 0) src_sh[j] = s;
            const float x = SS[s * HEADS + hh] + sdst_sh[hh];
            v_sh[j * 9 + hh] = x > 0.f ? x : 0.01f * x;
        }
        __syncthreads();
        // B: per-head chunk max -> exp -> sum
        float cm = -1e30f;
#pragma unroll
        for (int k = 0; k < 4; ++k) {
            const int j = g32 + k * 32;
            if (j < cnt) cm = fmaxf(cm, v_sh[j * 9 + h]);
        }
#pragma unroll
        for (int off = 1; off < 32; off <<= 1) cm = fmaxf(cm, __shfl_xor(cm, off));
        const float m_new = fmaxf(m_run, cm);
        const float f = expf(m_run - m_new);
        float ps = 0.f;
#pragma unroll
        for (int k = 0; k < 4; ++k) {
            const int j = g32 + k * 32;
            if (j < cnt) {
                const float e = expf(v_sh[j * 9 + h] - m_new);
                v_sh[j * 9 + h] = e;
                ps += e;
            }
        }
#pragma unroll
        for (int off = 1; off < 32; off <<= 1) ps += __shfl_xor(ps, off);
        s_run = s_run * f + ps;
        m_run = m_new;
        accx *= f; accy *= f;
        __syncthreads();
        // C: accumulate unnormalized alpha * z — unroll 8 for MLP
        int j = 0;
        for (; j + 8 <= cnt; j += 8) {
            int   sv[8];
            float av[8];
            ushort2 zv[8];
#pragma unroll
            for (int u = 0; u < 8; ++u) {
                sv[u] = src_sh[j + u];
                av[u] = v_sh[(j + u) * 9 + h];
            }
#pragma unroll
            for (int u = 0; u < 8; ++u)
                zv[u] = *reinterpret_cast<const ushort2*>(&Zb[(size_t)sv[u] * NHID + d0]);
#pragma unroll
            for (int u = 0; u < 8; ++u) {
                accx = fmaf(av[u], bf2f(zv[u].x), accx);
                accy = fmaf(av[u], bf2f(zv[u].y), accy);
            }
        }
        for (; j < cnt; ++j) {
            const int s = src_sh[j];
            const float a = v_sh[j * 9 + h];
            const ushort2 zv = *reinterpret_cast<const ushort2*>(&Zb[(size_t)s * NHID + d0]);
            accx = fmaf(a, bf2f(zv.x), accx);
            accy = fmaf(a, bf2f(zv.y), accy);
        }
        __syncthreads();
    }

    const float inv = deg > 0 ? 1.f / s_run : 0.f;
    accx *= inv; accy *= inv;

    const size_t oin  = (size_t)n * NHID + d0;
    const size_t oout = (size_t)bi * NHID + d0;   // == oin when gl == nullptr
    const float2 hv = *reinterpret_cast<const float2*>(&Hin[oin]);
    const float ex = accx > 0.f ? accx : expm1f(accx);
    const float ey = accy > 0.f ? accy : expm1f(accy);
    const float rx = ex + hv.x, ry = ey + hv.y;
    *reinterpret_cast<float2*>(&Gf[oout]) = make_float2(rx, ry);
    *reinterpret_cast<ushort2*>(&Gb[oout]) = make_ushort2(f2bf(rx), f2bf(ry));
}

// ---------------------------------------------------------------------------
// LN( Y + b2 + R ) * g + b  -> Hf (fp32) and optionally Hb (bf16)
// ---------------------------------------------------------------------------
__global__ __launch_bounds__(256)
void ffn_ln(const float* __restrict__ Y, const float* __restrict__ b2,
            const float* __restrict__ gw, const float* __restrict__ bw,
            const float* __restrict__ R, float* __restrict__ Hf,
            ushort_t* __restrict__ Hb, int M)
{
    const int wave = threadIdx.x >> 6, lane = threadIdx.x & 63;
    const int n = blockIdx.x * 4 + wave;
    if (n >= M) return;
    const int f0 = lane * 8;
    const size_t o = (size_t)n * NHID + f0;

    const float4 ya = *reinterpret_cast<const float4*>(&Y[o]);
    const float4 yb = *reinterpret_cast<const float4*>(&Y[o + 4]);
    const float4 ha = *reinterpret_cast<const float4*>(&R[o]);
    const float4 hb = *reinterpret_cast<const float4*>(&R[o + 4]);
    const float4 ba = *reinterpret_cast<const float4*>(&b2[f0]);
    const float4 bb = *reinterpret_cast<const float4*>(&b2[f0 + 4]);

    float v[8] = { ya.x + ba.x + ha.x, ya.y + ba.y + ha.y,
                   ya.z + ba.z + ha.z, ya.w + ba.w + ha.w,
                   yb.x + bb.x + hb.x, yb.y + bb.y + hb.y,
                   yb.z + bb.z + hb.z, yb.w + bb.w + hb.w };
    float sum = 0.f;
#pragma unroll
    for (int k = 0; k < 8; ++k) sum += v[k];
#pragma unroll
    for (int off = 1; off < 64; off <<= 1) sum += __shfl_xor(sum, off);
    const float mu = sum * (1.f / NHID);
    float var = 0.f;
#pragma unroll
    for (int k = 0; k < 8; ++k) { const float d = v[k] - mu; var = fmaf(d, d, var); }
#pragma unroll
    for (int off = 1; off < 64; off <<= 1) var += __shfl_xor(var, off);
    var *= (1.f / NHID);
    const float inv = rsqrtf(var + LN_EPS);

    const float4 ga = *reinterpret_cast<const float4*>(&gw[f0]);
    const float4 gb = *reinterpret_cast<const float4*>(&gw[f0 + 4]);
    const float4 wa = *reinterpret_cast<const float4*>(&bw[f0]);
    const float4 wb = *reinterpret_cast<const float4*>(&bw[f0 + 4]);
    const float gg[8] = { ga.x, ga.y, ga.z, ga.w, gb.x, gb.y, gb.z, gb.w };
    const float ww[8] = { wa.x, wa.y, wa.z, wa.w, wb.x, wb.y, wb.z, wb.w };

    float r[8];
#pragma unroll
    for (int k = 0; k < 8; ++k) r[k] = (v[k] - mu) * inv * gg[k] + ww[k];

    *reinterpret_cast<float4*>(&Hf[o])     = make_float4(r[0], r[1], r[2], r[3]);
    *reinterpret_cast<float4*>(&Hf[o + 4]) = make_float4(r[4], r[5], r[6], r[7]);
    if (Hb) {
        *reinterpret_cast<ushort4*>(&Hb[o])     = make_ushort4(f2bf(r[0]), f2bf(r[1]), f2bf(r[2]), f2bf(r[3]));
        *reinterpret_cast<ushort4*>(&Hb[o + 4]) = make_ushort4(f2bf(r[4]), f2bf(r[5]), f2bf(r[6]), f2bf(r[7]));
    }
}

// ---------------------------------------------------------------------------
extern "C" void kernel_launch(void* const* d_in, const int* in_sizes, int n_in,
                              void* d_out, int out_size, void* d_ws, size_t ws_size,
                              hipStream_t stream)
{
    const float* feats = (const float*)d_in[0];
    const float* Wh    = (const float*)d_in[1];
    const float* al    = (const float*)d_in[2];
    const float* ar    = (const float*)d_in[3];
    const float* w1    = (const float*)d_in[4];
    const float* b1    = (const float*)d_in[5];
    const float* w2    = (const float*)d_in[6];
    const float* b2    = (const float*)d_in[7];
    const float* ln_g  = (const float*)d_in[8];
    const float* ln_b  = (const float*)d_in[9];
    const int* esrc    = (const int*)d_in[10];
    const int* edst    = (const int*)d_in[11];
    const int* sent    = (const int*)d_in[12];
    float* out = (float*)d_out;

    char* ws = (char*)d_ws;
    size_t off = 0;
    auto alloc = [&](size_t bytes) -> void* {
        void* p = ws + off;
        off = (off + bytes + 255) & ~(size_t)255;
        return p;
    };
    float*    H   = (float*)alloc((size_t)NN * NHID * 4);
    float*    Y   = (float*)alloc((size_t)NN * NHID * 4);   // FFN output (fp32)
    ushort_t* Hb  = (ushort_t*)alloc((size_t)NN * NHID * 2);
    ushort_t* Zb  = (ushort_t*)alloc((size_t)NN * NHID * 2);
    float*    Gf  = (float*)alloc((size_t)NS * NHID * 4);   // gathered post-GAT (p=1)
    ushort_t* Gb  = (ushort_t*)alloc((size_t)NS * NHID * 2);
    float*    SS  = (float*)alloc((size_t)NN * HEADS * 4);
    float*    SD  = (float*)alloc((size_t)NN * HEADS * 4);
    ushort_t* Wpb = (ushort_t*)alloc((size_t)NHID * NHID * 2);
    ushort_t* w1b = (ushort_t*)alloc((size_t)FH * NHID * 2);
    ushort_t* w2b = (ushort_t*)alloc((size_t)NHID * FH * 2);
    int* rowptr = (int*)alloc((NN + 1) * 4);
    int* deg    = (int*)alloc(NN * 4);
    int* cursor = (int*)alloc(NN * 4);
    int* csrc   = (int*)alloc((size_t)NE * 4);
    // FFN mid chunk (bf16): as large as remaining workspace allows
    int CH = FH;
    while (CH > 128 && off + (size_t)NN * CH * 2 > ws_size) CH >>= 1;
    ushort_t* MIDb = (ushort_t*)alloc((size_t)NN * CH * 2);

    // ---- CSR build ----
    hipMemsetAsync(deg, 0, NN * 4, stream);
    count_deg<<<(NE + 255) / 256, 256, 0, stream>>>(edst, deg);
    scan_deg<<<1, 1024, 0, stream>>>(deg, rowptr);
    copy_int<<<(NN + 255) / 256, 256, 0, stream>>>(rowptr, cursor, NN);
    scatter_edges<<<(NE + 255) / 256, 256, 0, stream>>>(esrc, edst, cursor, csrc);

    // ---- weights -> bf16 (once) ----
    f2b_kernel<<<(FH * NHID / 4 + 255) / 256, 256, 0, stream>>>(w1, w1b, FH * NHID);
    f2b_kernel<<<(NHID * FH / 4 + 255) / 256, 256, 0, stream>>>(w2, w2b, NHID * FH);

    // ---- h = feats (fp32 master + bf16 copy, one pass) ----
    feats_init<<<(NN * NHID / 4 + 255) / 256, 256, 0, stream>>>(feats, H, Hb, NN * NHID);

    const int MT  = (NN + 127) / 128;   // 157 m-tiles (full)
    const int MTs = (NS + 127) / 128;   // 16 m-tiles (sent rows)
    for (int p = 0; p < 2; ++p) {
        // z = h @ Wh[p]  (bf16 MFMA, bf16 out) + fused attention scores (ALL nodes)
        repack_wb<<<(NHID * NHID + 255) / 256, 256, 0, stream>>>(
            Wh + (size_t)p * HEADS * NHID * HD, Wpb);
        mfma_gemm_nt<0, 0, 1, 1><<<dim3(NHID / 128, MT), 256, 0, stream>>>(
            Hb, Wpb, Zb, nullptr,
            al + (size_t)p * HEADS * HD, ar + (size_t)p * HEADS * HD, SS, SD,
            NN, NHID, NHID, NHID, NHID, NHID);

        if (p == 0) {
            // full aggregate (in place) + full FFN
            gat_aggregate<<<NN, 256, 0, stream>>>(
                Zb, SS, SD, rowptr, csrc, nullptr, H, H, Hb);
            for (int c0 = 0; c0 < FH; c0 += CH) {
                mfma_gemm_nt<1, 0, 1, 0><<<dim3(CH / 128, MT), 256, 0, stream>>>(
                    Hb, w1b + (size_t)c0 * NHID, MIDb, b1 + c0,
                    nullptr, nullptr, nullptr, nullptr,
                    NN, CH, NHID, NHID, NHID, CH);
                if (c0 == 0)
                    mfma_gemm_nt<0, 0, 0, 0><<<dim3(NHID / 128, MT), 256, 0, stream>>>(
                        MIDb, w2b + c0, Y, nullptr,
                        nullptr, nullptr, nullptr, nullptr,
                        NN, NHID, CH, CH, FH, NHID);
                else
                    mfma_gemm_nt<0, 1, 0, 0><<<dim3(NHID / 128, MT), 256, 0, stream>>>(
                        MIDb, w2b + c0, Y, nullptr,
                        nullptr, nullptr, nullptr, nullptr,
                        NN, NHID, CH, CH, FH, NHID);
            }
            ffn_ln<<<(NN + 3) / 4, 256, 0, stream>>>(
                Y, b2, ln_g, ln_b, H, H, Hb, NN);
        } else {
            // LAST prop step: only sent rows needed after aggregation.
            gat_aggregate<<<NS, 256, 0, stream>>>(
                Zb, SS, SD, rowptr, csrc, sent, H, Gf, Gb);
            for (int c0 = 0; c0 < FH; c0 += CH) {
                mfma_gemm_nt<1, 0, 1, 0><<<dim3(CH / 128, MTs), 256, 0, stream>>>(
                    Gb, w1b + (size_t)c0 * NHID, MIDb, b1 + c0,
                    nullptr, nullptr, nullptr, nullptr,
                    NS, CH, NHID, NHID, NHID, CH);
                if (c0 == 0)
                    mfma_gemm_nt<0, 0, 0, 0><<<dim3(NHID / 128, MTs), 256, 0, stream>>>(
                        MIDb, w2b + c0, Y, nullptr,
                        nullptr, nullptr, nullptr, nullptr,
                        NS, NHID, CH, CH, FH, NHID);
                else
                    mfma_gemm_nt<0, 1, 0, 0><<<dim3(NHID / 128, MTs), 256, 0, stream>>>(
                        MIDb, w2b + c0, Y, nullptr,
                        nullptr, nullptr, nullptr, nullptr,
                        NS, NHID, CH, CH, FH, NHID);
            }
            ffn_ln<<<(NS + 3) / 4, 256, 0, stream>>>(
                Y, b2, ln_g, ln_b, Gf, out, nullptr, NS);
        }
    }
}